// Round 8
// baseline (8535.783 us; speedup 1.0000x reference)
//
#include <hip/hip_runtime.h>

// ============================================================================
// PointNet++ (8 batches, N=4096) forward on MI355X — full pipeline, fp32.
// Round 8: multi-batch FPS — each block runs 4 independent batch instances,
// so the ~1550-cyc/step serial overhead (barrier + LDS latency + merge) is
// amortized 4x. Named v2f registers (no arrays -> no spill), packed-f32 dist
// with deferred index recovery, winner-xyz carried through the reduction.
// Fusion graph unchanged: fuse1 = fps1||q1, fuse2 = fps2||bq1||t1,
// fuse3 = sa_pool1||bq2||t2||concat3.
// ============================================================================

constexpr int NBATCH = 8;

typedef float v2f __attribute__((ext_vector_type(2)));

// ---- DPP wave64 reduction helpers -----------------------------------------
template<int CTRL>
__device__ __forceinline__ float dpp_max_step(float v) {
  int o = __builtin_amdgcn_update_dpp(__float_as_int(v), __float_as_int(v),
                                      CTRL, 0xf, 0xf, false);  // invalid -> old(=v)
  return fmaxf(v, __int_as_float(o));
}
__device__ __forceinline__ float wave_max_bcast(float v) {
  v = dpp_max_step<0x111>(v);  // row_shr:1
  v = dpp_max_step<0x112>(v);  // row_shr:2
  v = dpp_max_step<0x114>(v);  // row_shr:4
  v = dpp_max_step<0x118>(v);  // row_shr:8
  v = dpp_max_step<0x142>(v);  // row_bcast:15
  v = dpp_max_step<0x143>(v);  // row_bcast:31
  return __int_as_float(__builtin_amdgcn_readlane(__float_as_int(v), 63));
}
template<int CTRL>
__device__ __forceinline__ int dpp_add_step(int v) {
  int o = __builtin_amdgcn_update_dpp(0, v, CTRL, 0xf, 0xf, true);  // invalid -> 0
  return v + o;
}
__device__ __forceinline__ int wave_sum_bcast(int v) {
  v = dpp_add_step<0x111>(v);
  v = dpp_add_step<0x112>(v);
  v = dpp_add_step<0x114>(v);
  v = dpp_add_step<0x118>(v);
  v = dpp_add_step<0x142>(v);
  v = dpp_add_step<0x143>(v);
  return __builtin_amdgcn_readlane(v, 63);
}

// ---------------------------------------------------------------------------
// Multi-batch FPS. One block handles 4 independent batches; per combined step:
// 4x {packed dist+min update, deferred per-lane argmax recovery, DPP wave max,
// ballot lowest-lane, winner xyz readlane'd, lane0 -> LDS}, ONE barrier,
// 4x {8-key merge, winner xyz from LDS, t0 appends center to LDS scb}.
// Exact semantics: fmin/fmax are rounding-free; equality recovery with
// descending overwrite == first-index-of-max; ballot lowest lane + ~gidx key
// == jnp.argmax first-occurrence ties.
// ---------------------------------------------------------------------------
#define DIST_PAIR(PX, PY, PZ, MD) { \
  v2f dx = PX - cxv; v2f dy = PY - cyv; v2f dz = PZ - czv; \
  v2f d = (dx * dx + dy * dy) + dz * dz; \
  MD = __builtin_elementwise_min(MD, d); \
  bv2 = __builtin_elementwise_max(bv2, MD); }

// ---- fps1: NPTS=4096, NTH=512, PT=8 (4 v2f pairs), NSAMP=2048 --------------
__device__ void fps1_quad(const float* __restrict__ pos4, float* __restrict__ cb4) {
#pragma clang fp contract(off)
  constexpr int NPTS = 4096, NTH = 512, PT = 8, NW = 8, NSAMP = 2048;
  __shared__ unsigned long long skey[2][4][NW];
  __shared__ float sxyz[2][4][NW][3];
  __shared__ float scb[4][NSAMP * 3];
  const int t = threadIdx.x, lane = t & 63, w = t >> 6;
  const float INF = __builtin_inff();

#define F1_REGS(B) \
  v2f px0_##B, px1_##B, px2_##B, px3_##B; \
  v2f py0_##B, py1_##B, py2_##B, py3_##B; \
  v2f pz0_##B, pz1_##B, pz2_##B, pz3_##B; \
  v2f md0_##B, md1_##B, md2_##B, md3_##B; \
  float cx_##B, cy_##B, cz_##B;
  F1_REGS(0) F1_REGS(1) F1_REGS(2) F1_REGS(3)

#define F1_LOAD(B) { \
  const float* pp = pos4 + (size_t)(B) * NPTS * 3; \
  int jb = t * PT; \
  px0_##B = (v2f){pp[(jb+0)*3+0], pp[(jb+1)*3+0]}; \
  py0_##B = (v2f){pp[(jb+0)*3+1], pp[(jb+1)*3+1]}; \
  pz0_##B = (v2f){pp[(jb+0)*3+2], pp[(jb+1)*3+2]}; \
  px1_##B = (v2f){pp[(jb+2)*3+0], pp[(jb+3)*3+0]}; \
  py1_##B = (v2f){pp[(jb+2)*3+1], pp[(jb+3)*3+1]}; \
  pz1_##B = (v2f){pp[(jb+2)*3+2], pp[(jb+3)*3+2]}; \
  px2_##B = (v2f){pp[(jb+4)*3+0], pp[(jb+5)*3+0]}; \
  py2_##B = (v2f){pp[(jb+4)*3+1], pp[(jb+5)*3+1]}; \
  pz2_##B = (v2f){pp[(jb+4)*3+2], pp[(jb+5)*3+2]}; \
  px3_##B = (v2f){pp[(jb+6)*3+0], pp[(jb+7)*3+0]}; \
  py3_##B = (v2f){pp[(jb+6)*3+1], pp[(jb+7)*3+1]}; \
  pz3_##B = (v2f){pp[(jb+6)*3+2], pp[(jb+7)*3+2]}; \
  md0_##B = (v2f){INF, INF}; md1_##B = (v2f){INF, INF}; \
  md2_##B = (v2f){INF, INF}; md3_##B = (v2f){INF, INF}; \
  cx_##B = pp[0]; cy_##B = pp[1]; cz_##B = pp[2]; \
  if (t == 0) { scb[B][0] = cx_##B; scb[B][1] = cy_##B; scb[B][2] = cz_##B; } }
  F1_LOAD(0) F1_LOAD(1) F1_LOAD(2) F1_LOAD(3)

#define F1_PHASEA(B) { \
  v2f cxv = {cx_##B, cx_##B}, cyv = {cy_##B, cy_##B}, czv = {cz_##B, cz_##B}; \
  v2f bv2 = (v2f){-INF, -INF}; \
  DIST_PAIR(px0_##B, py0_##B, pz0_##B, md0_##B) \
  DIST_PAIR(px1_##B, py1_##B, pz1_##B, md1_##B) \
  DIST_PAIR(px2_##B, py2_##B, pz2_##B, md2_##B) \
  DIST_PAIR(px3_##B, py3_##B, pz3_##B, md3_##B) \
  float bv = fmaxf(bv2.x, bv2.y); \
  int bi = 0; \
  if (md3_##B.y == bv) bi = 7; \
  if (md3_##B.x == bv) bi = 6; \
  if (md2_##B.y == bv) bi = 5; \
  if (md2_##B.x == bv) bi = 4; \
  if (md1_##B.y == bv) bi = 3; \
  if (md1_##B.x == bv) bi = 2; \
  if (md0_##B.y == bv) bi = 1; \
  if (md0_##B.x == bv) bi = 0; \
  float wmax = wave_max_bcast(bv); \
  unsigned long long ball = __ballot(bv == wmax); \
  int fl = __ffsll((long long)ball) - 1; \
  int ib = __builtin_amdgcn_readlane(bi, fl); \
  int gidx = ((w << 6) + fl) * PT + ib; \
  int kk = ib >> 1; \
  v2f sx = px0_##B, sy = py0_##B, sz = pz0_##B; \
  if (kk == 1) { sx = px1_##B; sy = py1_##B; sz = pz1_##B; } \
  if (kk == 2) { sx = px2_##B; sy = py2_##B; sz = pz2_##B; } \
  if (kk == 3) { sx = px3_##B; sy = py3_##B; sz = pz3_##B; } \
  float wx = (ib & 1) ? sx.y : sx.x; \
  float wy = (ib & 1) ? sy.y : sy.x; \
  float wz = (ib & 1) ? sz.y : sz.x; \
  wx = __int_as_float(__builtin_amdgcn_readlane(__float_as_int(wx), fl)); \
  wy = __int_as_float(__builtin_amdgcn_readlane(__float_as_int(wy), fl)); \
  wz = __int_as_float(__builtin_amdgcn_readlane(__float_as_int(wz), fl)); \
  if (lane == 0) { \
    skey[s & 1][B][w] = (((unsigned long long)(unsigned)__float_as_int(wmax)) << 32) \
                        | (unsigned)(~gidx); \
    sxyz[s & 1][B][w][0] = wx; sxyz[s & 1][B][w][1] = wy; sxyz[s & 1][B][w][2] = wz; } }

#define F1_PHASEB(B) { \
  unsigned long long best = skey[s & 1][B][0]; int qw = 0; \
  _Pragma("unroll") \
  for (int q = 1; q < NW; q++) { \
    unsigned long long k2 = skey[s & 1][B][q]; \
    if (k2 > best) { best = k2; qw = q; } } \
  cx_##B = sxyz[s & 1][B][qw][0]; \
  cy_##B = sxyz[s & 1][B][qw][1]; \
  cz_##B = sxyz[s & 1][B][qw][2]; \
  if (t == 0) { scb[B][(s + 1) * 3 + 0] = cx_##B; \
                scb[B][(s + 1) * 3 + 1] = cy_##B; \
                scb[B][(s + 1) * 3 + 2] = cz_##B; } }

  for (int s = 0; s < NSAMP - 1; ++s) {
    F1_PHASEA(0) F1_PHASEA(1) F1_PHASEA(2) F1_PHASEA(3)
    __syncthreads();
    F1_PHASEB(0) F1_PHASEB(1) F1_PHASEB(2) F1_PHASEB(3)
  }
  __syncthreads();
#pragma unroll
  for (int B = 0; B < 4; B++)
    for (int i = t; i < NSAMP * 3; i += NTH)
      cb4[(size_t)B * NSAMP * 3 + i] = scb[B][i];
#undef F1_REGS
#undef F1_LOAD
#undef F1_PHASEA
#undef F1_PHASEB
}

// ---- fps2: NPTS=2048, NTH=512, PT=4 (2 v2f pairs), NSAMP=512 ---------------
__device__ void fps2_quad(const float* __restrict__ pos4, float* __restrict__ cb4) {
#pragma clang fp contract(off)
  constexpr int NPTS = 2048, NTH = 512, PT = 4, NW = 8, NSAMP = 512;
  __shared__ unsigned long long skey2[2][4][NW];
  __shared__ float sxyz2[2][4][NW][3];
  __shared__ float scb2[4][NSAMP * 3];
  const int t = threadIdx.x, lane = t & 63, w = t >> 6;
  const float INF = __builtin_inff();

#define F2_REGS(B) \
  v2f px0_##B, px1_##B, py0_##B, py1_##B, pz0_##B, pz1_##B; \
  v2f md0_##B, md1_##B; \
  float cx_##B, cy_##B, cz_##B;
  F2_REGS(0) F2_REGS(1) F2_REGS(2) F2_REGS(3)

#define F2_LOAD(B) { \
  const float* pp = pos4 + (size_t)(B) * NPTS * 3; \
  int jb = t * PT; \
  px0_##B = (v2f){pp[(jb+0)*3+0], pp[(jb+1)*3+0]}; \
  py0_##B = (v2f){pp[(jb+0)*3+1], pp[(jb+1)*3+1]}; \
  pz0_##B = (v2f){pp[(jb+0)*3+2], pp[(jb+1)*3+2]}; \
  px1_##B = (v2f){pp[(jb+2)*3+0], pp[(jb+3)*3+0]}; \
  py1_##B = (v2f){pp[(jb+2)*3+1], pp[(jb+3)*3+1]}; \
  pz1_##B = (v2f){pp[(jb+2)*3+2], pp[(jb+3)*3+2]}; \
  md0_##B = (v2f){INF, INF}; md1_##B = (v2f){INF, INF}; \
  cx_##B = pp[0]; cy_##B = pp[1]; cz_##B = pp[2]; \
  if (t == 0) { scb2[B][0] = cx_##B; scb2[B][1] = cy_##B; scb2[B][2] = cz_##B; } }
  F2_LOAD(0) F2_LOAD(1) F2_LOAD(2) F2_LOAD(3)

#define F2_PHASEA(B) { \
  v2f cxv = {cx_##B, cx_##B}, cyv = {cy_##B, cy_##B}, czv = {cz_##B, cz_##B}; \
  v2f bv2 = (v2f){-INF, -INF}; \
  DIST_PAIR(px0_##B, py0_##B, pz0_##B, md0_##B) \
  DIST_PAIR(px1_##B, py1_##B, pz1_##B, md1_##B) \
  float bv = fmaxf(bv2.x, bv2.y); \
  int bi = 0; \
  if (md1_##B.y == bv) bi = 3; \
  if (md1_##B.x == bv) bi = 2; \
  if (md0_##B.y == bv) bi = 1; \
  if (md0_##B.x == bv) bi = 0; \
  float wmax = wave_max_bcast(bv); \
  unsigned long long ball = __ballot(bv == wmax); \
  int fl = __ffsll((long long)ball) - 1; \
  int ib = __builtin_amdgcn_readlane(bi, fl); \
  int gidx = ((w << 6) + fl) * PT + ib; \
  int kk = ib >> 1; \
  v2f sx = px0_##B, sy = py0_##B, sz = pz0_##B; \
  if (kk == 1) { sx = px1_##B; sy = py1_##B; sz = pz1_##B; } \
  float wx = (ib & 1) ? sx.y : sx.x; \
  float wy = (ib & 1) ? sy.y : sy.x; \
  float wz = (ib & 1) ? sz.y : sz.x; \
  wx = __int_as_float(__builtin_amdgcn_readlane(__float_as_int(wx), fl)); \
  wy = __int_as_float(__builtin_amdgcn_readlane(__float_as_int(wy), fl)); \
  wz = __int_as_float(__builtin_amdgcn_readlane(__float_as_int(wz), fl)); \
  if (lane == 0) { \
    skey2[s & 1][B][w] = (((unsigned long long)(unsigned)__float_as_int(wmax)) << 32) \
                         | (unsigned)(~gidx); \
    sxyz2[s & 1][B][w][0] = wx; sxyz2[s & 1][B][w][1] = wy; sxyz2[s & 1][B][w][2] = wz; } }

#define F2_PHASEB(B) { \
  unsigned long long best = skey2[s & 1][B][0]; int qw = 0; \
  _Pragma("unroll") \
  for (int q = 1; q < NW; q++) { \
    unsigned long long k2 = skey2[s & 1][B][q]; \
    if (k2 > best) { best = k2; qw = q; } } \
  cx_##B = sxyz2[s & 1][B][qw][0]; \
  cy_##B = sxyz2[s & 1][B][qw][1]; \
  cz_##B = sxyz2[s & 1][B][qw][2]; \
  if (t == 0) { scb2[B][(s + 1) * 3 + 0] = cx_##B; \
                scb2[B][(s + 1) * 3 + 1] = cy_##B; \
                scb2[B][(s + 1) * 3 + 2] = cz_##B; } }

  for (int s = 0; s < NSAMP - 1; ++s) {
    F2_PHASEA(0) F2_PHASEA(1) F2_PHASEA(2) F2_PHASEA(3)
    __syncthreads();
    F2_PHASEB(0) F2_PHASEB(1) F2_PHASEB(2) F2_PHASEB(3)
  }
  __syncthreads();
#pragma unroll
  for (int B = 0; B < 4; B++)
    for (int i = t; i < NSAMP * 3; i += NTH)
      cb4[(size_t)B * NSAMP * 3 + i] = scb2[B][i];
#undef F2_REGS
#undef F2_LOAD
#undef F2_PHASEA
#undef F2_PHASEB
}

// ---------------------------------------------------------------------------
// Ball query + exact 64 nearest within radius (one wave per center).
// WPB waves per block, LCAP candidate capacity per wave.
// ---------------------------------------------------------------------------
template<int NPTS, int SPB, int LCAP, int WPB>
__device__ void ballquery_body(int bb, const float* __restrict__ pts,
    const float* __restrict__ ctr, float rr,
    int* __restrict__ nbr, int* __restrict__ cnt_out) {
#pragma clang fp contract(off)
  constexpr int KREG = LCAP / 64;
  const int gw = bb * WPB + (threadIdx.x >> 6);
  const int lane = threadIdx.x & 63;
  const int b = gw / SPB;
  __shared__ unsigned long long list_[WPB][LCAP];
  unsigned long long* list = list_[threadIdx.x >> 6];
  const float* p = pts + (size_t)b * NPTS * 3;
  const float* c = ctr + (size_t)gw * 3;
  const float cx = c[0], cy = c[1], cz = c[2];
  const unsigned long long lmask = (1ull << lane) - 1ull;
  int cnt = 0;
  for (int j0 = 0; j0 < NPTS; j0 += 64) {
    int j = j0 + lane;
    float dx = p[j * 3 + 0] - cx, dy = p[j * 3 + 1] - cy, dz = p[j * 3 + 2] - cz;
    float d = (dx * dx + dy * dy) + dz * dz;
    bool in = (d <= rr);
    unsigned long long bal = __ballot(in);
    int pos = cnt + __popcll(bal & lmask);
    if (in && pos < LCAP)
      list[pos] = (((unsigned long long)__float_as_uint(d)) << 32) | (unsigned)j;
    cnt += __popcll(bal);
  }
  if (cnt > LCAP) cnt = LCAP;
  __syncthreads();
  int* nbrp = nbr + (size_t)gw * 64;
  const int nr = (cnt + 63) >> 6;
  unsigned long long key[KREG];
#pragma unroll
  for (int r = 0; r < KREG; r++) {
    int slot = r * 64 + lane;
    key[r] = (r < nr && slot < cnt) ? list[slot] : ~0ull;
  }
  if (cnt <= 64) {
    nbrp[lane] = (lane < cnt) ? (int)(unsigned)key[0] : 0;
    if (lane == 0) cnt_out[gw] = cnt;
    return;
  }
  // radix select on d2 bits (d2 < 2.0 -> bits 31:30 are 0)
  unsigned pref = 0; int cbase = 0;
  for (int bit = 29; bit >= 0; --bit) {
    int cc = 0;
#pragma unroll
    for (int r = 0; r < KREG; r++) if (r < nr) {
      unsigned db = (unsigned)(key[r] >> 32);
      cc += ((db >> bit) == (pref >> bit)) ? 1 : 0;
    }
    cc = wave_sum_bcast(cc);
    if (cbase + cc < 64) { cbase += cc; pref |= (1u << bit); }
  }
  int base = 0;
#pragma unroll
  for (int r = 0; r < KREG; r++) if (r < nr) {
    unsigned db = (unsigned)(key[r] >> 32);
    bool sel = db < pref;
    unsigned long long m = __ballot(sel);
    if (sel) nbrp[base + __popcll(m & lmask)] = (int)(unsigned)key[r];
    base += __popcll(m);
  }
  int need = 64 - base;
  for (int t2 = 0; t2 < need; ++t2) {
    unsigned besti = 0xffffffffu;
#pragma unroll
    for (int r = 0; r < KREG; r++) if (r < nr) {
      if ((unsigned)(key[r] >> 32) == pref) {
        unsigned v = (unsigned)key[r];
        besti = v < besti ? v : besti;
      }
    }
#pragma unroll
    for (int off = 32; off; off >>= 1) {
      unsigned o = __shfl_xor(besti, off, 64);
      besti = o < besti ? o : besti;
    }
    unsigned long long wk = (((unsigned long long)pref) << 32) | besti;
#pragma unroll
    for (int r = 0; r < KREG; r++) if (r < nr && key[r] == wk) key[r] = ~0ull;
    if (lane == 0) nbrp[base + t2] = (int)besti;
  }
  if (lane == 0) cnt_out[gw] = 64;
}

// ---- SA layer-1 split bodies ----------------------------------------------
__device__ void q1_body(int bb, const float* __restrict__ x,
    const float* __restrict__ pos, const float* __restrict__ w, float* __restrict__ q) {
  int gw = bb * 8 + (threadIdx.x >> 6), lane = threadIdx.x & 63;  // 512-thr blocks
  const float* xr = x + (size_t)gw * 3; const float* pr = pos + (size_t)gw * 3;
  float a = 0.f;
#pragma unroll
  for (int m = 0; m < 3; m++) a = fmaf(xr[m], w[m * 64 + lane], a);
#pragma unroll
  for (int m = 0; m < 3; m++) a = fmaf(pr[m], w[(3 + m) * 64 + lane], a);
  q[(size_t)gw * 64 + lane] = a;
}

__device__ void t1_body(int bb, const float* __restrict__ c1,
    const float* __restrict__ w, const float* __restrict__ b1, float* __restrict__ t) {
  int gw = bb * 8 + (threadIdx.x >> 6), lane = threadIdx.x & 63;  // 512-thr blocks
  const float* cr = c1 + (size_t)gw * 3;
  float a = b1[lane];
#pragma unroll
  for (int m = 0; m < 3; m++) a = fmaf(-cr[m], w[(3 + m) * 64 + lane], a);
  t[(size_t)gw * 64 + lane] = a;
}

__device__ void t2_body(int bb, const float* __restrict__ c2,
    const float* __restrict__ w, const float* __restrict__ b1, float* __restrict__ t) {
  int gw = (bb << 2) + (threadIdx.x >> 6), lane = threadIdx.x & 63;
  const float* cr = c2 + (size_t)gw * 3;
  float a0 = b1[lane], a1 = b1[64 + lane];
#pragma unroll
  for (int m = 0; m < 3; m++) {
    a0 = fmaf(-cr[m], w[(128 + m) * 128 + lane], a0);
    a1 = fmaf(-cr[m], w[(128 + m) * 128 + 64 + lane], a1);
  }
  t[(size_t)gw * 128 + lane] = a0;
  t[(size_t)gw * 128 + 64 + lane] = a1;
}

__device__ void concat3_body(int bb, const float* __restrict__ c2, float* __restrict__ xin3) {
  int row = bb * 256 + threadIdx.x;
  if (row < NBATCH * 512) {
    float* o = xin3 + (size_t)row * 272 + 256;
    const float* c = c2 + (size_t)row * 3;
    o[0] = c[0]; o[1] = c[1]; o[2] = c[2];
#pragma unroll
    for (int i = 3; i < 16; i++) o[i] = 0.f;
  }
}

// ---------------------------------------------------------------------------
// Per-center: h1[k] = relu(q[nbr_k] + t_s); h2 = h1 @ W2 + b2; out = max_k h2.
// ---------------------------------------------------------------------------
template<int CIN, int COUT, int OSTR, int NPB, int SPB>
__device__ void sa_pool_body(int bb, const float* __restrict__ q,
    const float* __restrict__ t, const int* __restrict__ nbr, const int* __restrict__ cnt,
    const float* __restrict__ w2, const float* __restrict__ b2, float* __restrict__ out) {
  int gw = (bb << 2) + (threadIdx.x >> 6), lane = threadIdx.x & 63;
  int b = gw / SPB;
  int nk = nbr[(size_t)gw * 64 + lane];
  int c = cnt[gw];
  const float* qr = q + ((size_t)b * NPB + nk) * CIN;
  const float* tr = t + (size_t)gw * CIN;
  float h[CIN];
#pragma unroll
  for (int i = 0; i < CIN; i += 4) {
    float4 v = *(const float4*)(qr + i);
    h[i]     = fmaxf(v.x + tr[i], 0.f);
    h[i + 1] = fmaxf(v.y + tr[i + 1], 0.f);
    h[i + 2] = fmaxf(v.z + tr[i + 2], 0.f);
    h[i + 3] = fmaxf(v.w + tr[i + 3], 0.f);
  }
  bool valid = lane < c;
  float* op = out + (size_t)gw * OSTR;
#pragma unroll 1
  for (int nc = 0; nc < COUT; nc += 16) {
    float acc[16];
#pragma unroll
    for (int u = 0; u < 16; u++) acc[u] = b2[nc + u];
#pragma unroll
    for (int i = 0; i < CIN; i++) {
      const float* wr = w2 + (size_t)i * COUT + nc;
#pragma unroll
      for (int u = 0; u < 16; u++) acc[u] = fmaf(h[i], wr[u], acc[u]);
    }
#pragma unroll
    for (int u = 0; u < 16; u++) {
      float v = valid ? acc[u] : -__builtin_inff();
#pragma unroll
      for (int off = 32; off; off >>= 1) v = fmaxf(v, __shfl_xor(v, off, 64));
      acc[u] = v;
    }
    if (lane == 0) {
#pragma unroll
      for (int u = 0; u < 16; u += 4)
        *(float4*)(op + nc + u) = make_float4(acc[u], acc[u + 1], acc[u + 2], acc[u + 3]);
    }
  }
}

// ---- fused kernels ---------------------------------------------------------
__global__ __launch_bounds__(512) void fuse1_kernel(const float* __restrict__ pos,
    const float* __restrict__ x, const float* __restrict__ w11,
    float* __restrict__ c1, float* __restrict__ q1) {
  int bid = blockIdx.x;
  if (bid < 2)
    fps1_quad(pos + (size_t)bid * 4 * 4096 * 3, c1 + (size_t)bid * 4 * 2048 * 3);
  else
    q1_body(bid - 2, x, pos, w11, q1);
}

__global__ __launch_bounds__(512) void fuse2_kernel(const float* __restrict__ pos,
    const float* __restrict__ c1, const float* __restrict__ w11, const float* __restrict__ b11,
    float* __restrict__ c2, int* __restrict__ nbr1, int* __restrict__ cnt1,
    float* __restrict__ t1buf, float rr1) {
  int bid = blockIdx.x;
  if (bid < 2)
    fps2_quad(c1 + (size_t)bid * 4 * 2048 * 3, c2 + (size_t)bid * 4 * 512 * 3);
  else if (bid < 2 + 2048)
    ballquery_body<4096, 2048, 512, 8>(bid - 2, pos, c1, rr1, nbr1, cnt1);
  else
    t1_body(bid - (2 + 2048), c1, w11, b11, t1buf);
}

__global__ __launch_bounds__(256) void fuse3_kernel(const float* __restrict__ q1buf,
    const float* __restrict__ t1buf, const int* __restrict__ nbr1, const int* __restrict__ cnt1,
    const float* __restrict__ w12, const float* __restrict__ b12, float* __restrict__ x1,
    const float* __restrict__ c1, const float* __restrict__ c2, float rr2,
    int* __restrict__ nbr2, int* __restrict__ cnt2,
    const float* __restrict__ w21, const float* __restrict__ b21, float* __restrict__ t2buf,
    float* __restrict__ xin3) {
  int bid = blockIdx.x;
  if (bid < 4096)
    sa_pool_body<64, 128, 128, 4096, 2048>(bid, q1buf, t1buf, nbr1, cnt1, w12, b12, x1);
  else if (bid < 4096 + 1024)
    ballquery_body<2048, 512, 1024, 4>(bid - 4096, c1, c2, rr2, nbr2, cnt2);
  else if (bid < 4096 + 1024 + 1024)
    t2_body(bid - (4096 + 1024), c2, w21, b21, t2buf);
  else
    concat3_body(bid - (4096 + 1024 + 1024), c2, xin3);
}

// SA2 layer-1 q: q2[j] = [x1_j,p1_j] @ W1 (131->128)
__global__ __launch_bounds__(256) void q2_kernel(const float* __restrict__ x1,
    const float* __restrict__ p1, const float* __restrict__ w, float* __restrict__ q2) {
  int gw = (blockIdx.x << 2) + (threadIdx.x >> 6), lane = threadIdx.x & 63;
  const float* xr = x1 + (size_t)gw * 128; const float* pr = p1 + (size_t)gw * 3;
  float a0 = 0.f, a1 = 0.f;
#pragma unroll 8
  for (int m = 0; m < 128; m++) {
    float v = xr[m];
    a0 = fmaf(v, w[m * 128 + lane], a0);
    a1 = fmaf(v, w[m * 128 + 64 + lane], a1);
  }
#pragma unroll
  for (int m = 0; m < 3; m++) {
    float v = pr[m];
    a0 = fmaf(v, w[(128 + m) * 128 + lane], a0);
    a1 = fmaf(v, w[(128 + m) * 128 + 64 + lane], a1);
  }
  q2[(size_t)gw * 128 + lane] = a0;
  q2[(size_t)gw * 128 + 64 + lane] = a1;
}

__global__ __launch_bounds__(256) void sa_pool2_kernel(const float* __restrict__ q,
    const float* __restrict__ t, const int* __restrict__ nbr, const int* __restrict__ cnt,
    const float* __restrict__ w2, const float* __restrict__ b2, float* __restrict__ out) {
  sa_pool_body<128, 256, 272, 2048, 512>(blockIdx.x, q, t, nbr, cnt, w2, b2, out);
}

// ---------------------------------------------------------------------------
// Tiled fp32 GEMM, 64x64 block tile, 256 threads (4x4 per thread), K-step 16.
// ---------------------------------------------------------------------------
template<int K, int KP, int N, int AST, bool RELU>
__global__ __launch_bounds__(256) void gemm64(const float* __restrict__ A,
    const float* __restrict__ W, const float* __restrict__ bias, float* __restrict__ C) {
  constexpr int NT = N / 64;
  const int bid = blockIdx.x, tid = threadIdx.x;
  const int tm = bid / NT, tn = bid % NT;
  __shared__ __align__(16) float As[16][68];
  __shared__ __align__(16) float Ws[16][68];
  const int arow = tid >> 2, acol = (tid & 3) << 2;
  const int wrow = tid >> 4, wcol = (tid & 15) << 2;
  const int ty = tid >> 4, tx = tid & 15;
  const float* Ap = A + (size_t)(tm * 64 + arow) * AST + acol;
  const float* Wp = W + (size_t)tn * 64 + wcol;
  float acc[4][4] = {};
  for (int k0 = 0; k0 < KP; k0 += 16) {
    float4 av = *(const float4*)(Ap + k0);
    As[acol + 0][arow] = av.x; As[acol + 1][arow] = av.y;
    As[acol + 2][arow] = av.z; As[acol + 3][arow] = av.w;
    int krow = k0 + wrow;
    float4 wv = make_float4(0.f, 0.f, 0.f, 0.f);
    if (krow < K) wv = *(const float4*)(Wp + (size_t)krow * N);
    *(float4*)(&Ws[wrow][wcol]) = wv;
    __syncthreads();
#pragma unroll
    for (int kk = 0; kk < 16; kk++) {
      float4 a4 = *(const float4*)(&As[kk][ty << 2]);
      float4 b4 = *(const float4*)(&Ws[kk][tx << 2]);
      float aa[4] = {a4.x, a4.y, a4.z, a4.w};
      float bb[4] = {b4.x, b4.y, b4.z, b4.w};
#pragma unroll
      for (int mm = 0; mm < 4; mm++)
#pragma unroll
        for (int nn = 0; nn < 4; nn++) acc[mm][nn] = fmaf(aa[mm], bb[nn], acc[mm][nn]);
    }
    __syncthreads();
  }
  const int m0 = tm * 64 + (ty << 2), n0 = tn * 64 + (tx << 2);
#pragma unroll
  for (int mm = 0; mm < 4; mm++) {
    float4 o;
    o.x = acc[mm][0] + bias[n0 + 0];
    o.y = acc[mm][1] + bias[n0 + 1];
    o.z = acc[mm][2] + bias[n0 + 2];
    o.w = acc[mm][3] + bias[n0 + 3];
    if (RELU) { o.x = fmaxf(o.x, 0.f); o.y = fmaxf(o.y, 0.f);
                o.z = fmaxf(o.z, 0.f); o.w = fmaxf(o.w, 0.f); }
    *(float4*)(C + (size_t)(m0 + mm) * N + n0) = o;
  }
}

// global max over 512 points per batch: [8,512,1024] -> [8,1024]
__global__ void gmax_kernel(const float* __restrict__ h, float* __restrict__ g) {
  int n = blockIdx.x * 256 + threadIdx.x;          // 8192 outputs
  int b = n >> 10, col = n & 1023;
  const float* p = h + ((size_t)b * 512) * 1024 + col;
  float m = -__builtin_inff();
  for (int j = 0; j < 512; j++) m = fmaxf(m, p[(size_t)j * 1024]);
  g[n] = m;
}

// head MLP: 1024 ->512 relu ->256 relu ->40. One block per batch.
__global__ __launch_bounds__(256) void head_kernel(const float* __restrict__ g,
    const float* __restrict__ w1, const float* __restrict__ b1,
    const float* __restrict__ w2, const float* __restrict__ b2,
    const float* __restrict__ w3, const float* __restrict__ b3,
    float* __restrict__ out) {
  int b = blockIdx.x, t = threadIdx.x;
  __shared__ float s1[1024];
  __shared__ float s2[512];
  *(float4*)(s1 + t * 4) = *(const float4*)(g + (size_t)b * 1024 + t * 4);
  __syncthreads();
  {
    float a0 = b1[t], a1 = b1[t + 256];
    for (int i = 0; i < 1024; i++) {
      float v = s1[i];
      a0 = fmaf(v, w1[(size_t)i * 512 + t], a0);
      a1 = fmaf(v, w1[(size_t)i * 512 + t + 256], a1);
    }
    s2[t] = fmaxf(a0, 0.f); s2[t + 256] = fmaxf(a1, 0.f);
  }
  __syncthreads();
  {
    float a = b2[t];
    for (int i = 0; i < 512; i++) a = fmaf(s2[i], w2[(size_t)i * 256 + t], a);
    s1[t] = fmaxf(a, 0.f);
  }
  __syncthreads();
  if (t < 40) {
    float a = b3[t];
    for (int i = 0; i < 256; i++) a = fmaf(s1[i], w3[(size_t)i * 40 + t], a);
    out[(size_t)b * 40 + t] = a;
  }
}

// ===========================================================================
extern "C" void kernel_launch(void* const* d_in, const int* in_sizes, int n_in,
                              void* d_out, int out_size, void* d_ws, size_t ws_size,
                              hipStream_t stream) {
  const float* x   = (const float*)d_in[0];
  const float* pos = (const float*)d_in[1];
  const float* w11 = (const float*)d_in[2];  const float* b11 = (const float*)d_in[3];
  const float* w12 = (const float*)d_in[4];  const float* b12 = (const float*)d_in[5];
  const float* w21 = (const float*)d_in[6];  const float* b21 = (const float*)d_in[7];
  const float* w22 = (const float*)d_in[8];  const float* b22 = (const float*)d_in[9];
  const float* w31 = (const float*)d_in[10]; const float* b31 = (const float*)d_in[11];
  const float* w32 = (const float*)d_in[12]; const float* b32 = (const float*)d_in[13];
  const float* w33 = (const float*)d_in[14]; const float* b33 = (const float*)d_in[15];
  const float* hw1 = (const float*)d_in[16]; const float* hb1 = (const float*)d_in[17];
  const float* hw2 = (const float*)d_in[18]; const float* hb2 = (const float*)d_in[19];
  const float* hw3 = (const float*)d_in[20]; const float* hb3 = (const float*)d_in[21];
  float* out = (float*)d_out;

  // workspace layout (aliased by liveness); total ~41.7 MB
  char* wsb = (char*)d_ws;
  int*   cnt1 = (int*)(wsb + 81920);       // 64K
  int*   cnt2 = (int*)(wsb + 147456);      // 16K
  float* c1   = (float*)(wsb + 163840);    // 192K  (= p1)
  float* c2   = (float*)(wsb + 360448);    // 48K   (= p2)
  float* g    = (float*)(wsb + 409600);    // 32K
  char* big = wsb + 524288;
  int*   nbr1 = (int*)(big + 0);           // 4M   } dead after sa_pool1
  float* q1   = (float*)(big + 4194304);   // 8M   } -> h3c aliases (16M)
  float* t1   = (float*)(big + 12582912);  // 4M   }
  float* h3c  = (float*)(big + 0);
  float* x1   = (float*)(big + 16777216);  // 8M   } dead after q2/sa_pool2
  int*   nbr2 = (int*)(big + 25165824);    // 1M   } -> h3b aliases (8M)
  float* h3b  = (float*)(big + 16777216);
  float* q2   = (float*)(big + 26214400);  // 8M   -> h3a aliases (4M)
  float* h3a  = (float*)(big + 26214400);
  float* t2   = (float*)(big + 34603008);  // 2M
  float* xin3 = (float*)(big + 36700160);  // 4.45M  [8*512, 272]

  const float RR1 = (float)(0.2 * 0.2);    // match python-traced f32 constants
  const float RR2 = (float)(0.4 * 0.4);

  // ---- stage 1: fps1(2 blocks x 4 batches) || q1 ----
  fuse1_kernel<<<2 + 4096, 512, 0, stream>>>(pos, x, w11, c1, q1);
  // ---- stage 2: fps2(2 blocks x 4 batches) || ballquery1 || t1 ----
  fuse2_kernel<<<2 + 2048 + 2048, 512, 0, stream>>>(pos, c1, w11, b11,
                                                    c2, nbr1, cnt1, t1, RR1);
  // ---- stage 3: sa_pool1 || ballquery2 || t2 || concat3 ----
  fuse3_kernel<<<4096 + 1024 + 1024 + 16, 256, 0, stream>>>(q1, t1, nbr1, cnt1,
      w12, b12, x1, c1, c2, RR2, nbr2, cnt2, w21, b21, t2, xin3);
  // ---- stage 4+: SA2 finish, global SA, head ----
  q2_kernel<<<4096, 256, 0, stream>>>(x1, c1, w21, q2);
  sa_pool2_kernel<<<1024, 256, 0, stream>>>(q2, t2, nbr2, cnt2, w22, b22, xin3);
  gemm64<259, 272, 256, 272, true ><<<256,  256, 0, stream>>>(xin3, w31, b31, h3a);
  gemm64<256, 256, 512, 256, true ><<<512,  256, 0, stream>>>(h3a,  w32, b32, h3b);
  gemm64<512, 512, 1024, 512, false><<<1024, 256, 0, stream>>>(h3b, w33, b33, h3c);
  gmax_kernel<<<32, 256, 0, stream>>>(h3c, g);
  head_kernel<<<NBATCH, 256, 0, stream>>>(g, hw1, hb1, hw2, hb2, hw3, hb3, out);

  (void)in_sizes; (void)n_in; (void)out_size; (void)ws_size;
}

// Round 9
// 4116.042 us; speedup vs baseline: 2.0738x; 2.0738x over previous
//
#include <hip/hip_runtime.h>

// ============================================================================
// PointNet++ (8 batches, N=4096) forward on MI355X — full pipeline, fp32.
// Round 9: FPS = single batch per block (8 blocks), 512 thr, packed-f32 dist
// in NAMED v2f registers, __launch_bounds__(512,2) to unlock the 256-VGPR
// budget (r5/r6/r8 all spilled under the compiler's default cap), deferred
// equality argmax recovery, winner-xyz carried through ONE fused LDS round.
// Fusion graph unchanged: fuse1 = fps1||q1, fuse2 = fps2||bq1||t1,
// fuse3 = sa_pool1||bq2||t2||concat3.  (Semantics validated by r8 absmax 0.)
// ============================================================================

constexpr int NBATCH = 8;

typedef float v2f __attribute__((ext_vector_type(2)));

// ---- DPP wave64 reduction helpers -----------------------------------------
template<int CTRL>
__device__ __forceinline__ float dpp_max_step(float v) {
  int o = __builtin_amdgcn_update_dpp(__float_as_int(v), __float_as_int(v),
                                      CTRL, 0xf, 0xf, false);  // invalid -> old(=v)
  return fmaxf(v, __int_as_float(o));
}
__device__ __forceinline__ float wave_max_bcast(float v) {
  v = dpp_max_step<0x111>(v);  // row_shr:1
  v = dpp_max_step<0x112>(v);  // row_shr:2
  v = dpp_max_step<0x114>(v);  // row_shr:4
  v = dpp_max_step<0x118>(v);  // row_shr:8
  v = dpp_max_step<0x142>(v);  // row_bcast:15
  v = dpp_max_step<0x143>(v);  // row_bcast:31
  return __int_as_float(__builtin_amdgcn_readlane(__float_as_int(v), 63));
}
template<int CTRL>
__device__ __forceinline__ int dpp_add_step(int v) {
  int o = __builtin_amdgcn_update_dpp(0, v, CTRL, 0xf, 0xf, true);  // invalid -> 0
  return v + o;
}
__device__ __forceinline__ int wave_sum_bcast(int v) {
  v = dpp_add_step<0x111>(v);
  v = dpp_add_step<0x112>(v);
  v = dpp_add_step<0x114>(v);
  v = dpp_add_step<0x118>(v);
  v = dpp_add_step<0x142>(v);
  v = dpp_add_step<0x143>(v);
  return __builtin_amdgcn_readlane(v, 63);
}

#define DIST_PAIR(PX, PY, PZ, MD) { \
  v2f dx = PX - cxv; v2f dy = PY - cyv; v2f dz = PZ - czv; \
  v2f d = (dx * dx + dy * dy) + dz * dz; \
  MD = __builtin_elementwise_min(MD, d); \
  bv2 = __builtin_elementwise_max(bv2, MD); }

// ---------------------------------------------------------------------------
// fps1: one batch, NPTS=4096, 512 thr, PT=8 (4 named v2f pairs), NSAMP=2048.
// Per step: packed dist+min update, deferred per-lane argmax (descending
// equality overwrite -> lowest slot), DPP wave max, ballot lowest-lane,
// winner xyz readlane'd; lane0 writes {key,xyz} to LDS; ONE barrier; 8-way
// cndmask-carry merge (all LDS loads hoisted) gives next center in regs.
// Centers accumulate in LDS scb; single coalesced dump at the end.
// ---------------------------------------------------------------------------
__device__ void fps1_one(const float* __restrict__ p, float* __restrict__ cb) {
#pragma clang fp contract(off)
  constexpr int NTH = 512, PT = 8, NW = 8, NSAMP = 2048;
  __shared__ unsigned long long skey[2][NW];
  __shared__ float sxyz[2][NW][3];
  __shared__ float scb[NSAMP * 3];
  const int t = threadIdx.x, lane = t & 63, w = t >> 6;
  const float INF = __builtin_inff();
  v2f px0, px1, px2, px3, py0, py1, py2, py3, pz0, pz1, pz2, pz3;
  v2f md0, md1, md2, md3;
  {
    int jb = t * PT;
    px0 = (v2f){p[(jb+0)*3+0], p[(jb+1)*3+0]};
    py0 = (v2f){p[(jb+0)*3+1], p[(jb+1)*3+1]};
    pz0 = (v2f){p[(jb+0)*3+2], p[(jb+1)*3+2]};
    px1 = (v2f){p[(jb+2)*3+0], p[(jb+3)*3+0]};
    py1 = (v2f){p[(jb+2)*3+1], p[(jb+3)*3+1]};
    pz1 = (v2f){p[(jb+2)*3+2], p[(jb+3)*3+2]};
    px2 = (v2f){p[(jb+4)*3+0], p[(jb+5)*3+0]};
    py2 = (v2f){p[(jb+4)*3+1], p[(jb+5)*3+1]};
    pz2 = (v2f){p[(jb+4)*3+2], p[(jb+5)*3+2]};
    px3 = (v2f){p[(jb+6)*3+0], p[(jb+7)*3+0]};
    py3 = (v2f){p[(jb+6)*3+1], p[(jb+7)*3+1]};
    pz3 = (v2f){p[(jb+6)*3+2], p[(jb+7)*3+2]};
    md0 = (v2f){INF, INF}; md1 = (v2f){INF, INF};
    md2 = (v2f){INF, INF}; md3 = (v2f){INF, INF};
  }
  float cx = p[0], cy = p[1], cz = p[2];
  if (t == 0) { scb[0] = cx; scb[1] = cy; scb[2] = cz; }
  for (int s = 0; s < NSAMP - 1; ++s) {
    v2f cxv = {cx, cx}, cyv = {cy, cy}, czv = {cz, cz};
    v2f bv2 = (v2f){-INF, -INF};
    DIST_PAIR(px0, py0, pz0, md0)
    DIST_PAIR(px1, py1, pz1, md1)
    DIST_PAIR(px2, py2, pz2, md2)
    DIST_PAIR(px3, py3, pz3, md3)
    float bv = fmaxf(bv2.x, bv2.y);
    int bi = 0;
    if (md3.y == bv) bi = 7;
    if (md3.x == bv) bi = 6;
    if (md2.y == bv) bi = 5;
    if (md2.x == bv) bi = 4;
    if (md1.y == bv) bi = 3;
    if (md1.x == bv) bi = 2;
    if (md0.y == bv) bi = 1;
    if (md0.x == bv) bi = 0;
    float wmax = wave_max_bcast(bv);
    unsigned long long ball = __ballot(bv == wmax);
    int fl = __ffsll((long long)ball) - 1;       // lowest lane = lowest index
    int ib = __builtin_amdgcn_readlane(bi, fl);  // wave-uniform slot
    int gidx = ((w << 6) + fl) * PT + ib;
    int kk = ib >> 1;
    v2f sx = px0, sy = py0, sz = pz0;
    if (kk == 1) { sx = px1; sy = py1; sz = pz1; }
    if (kk == 2) { sx = px2; sy = py2; sz = pz2; }
    if (kk == 3) { sx = px3; sy = py3; sz = pz3; }
    float wx = (ib & 1) ? sx.y : sx.x;
    float wy = (ib & 1) ? sy.y : sy.x;
    float wz = (ib & 1) ? sz.y : sz.x;
    wx = __int_as_float(__builtin_amdgcn_readlane(__float_as_int(wx), fl));
    wy = __int_as_float(__builtin_amdgcn_readlane(__float_as_int(wy), fl));
    wz = __int_as_float(__builtin_amdgcn_readlane(__float_as_int(wz), fl));
    if (lane == 0) {
      skey[s & 1][w] = (((unsigned long long)(unsigned)__float_as_int(wmax)) << 32)
                       | (unsigned)(~gidx);
      sxyz[s & 1][w][0] = wx; sxyz[s & 1][w][1] = wy; sxyz[s & 1][w][2] = wz;
    }
    __syncthreads();
    unsigned long long best = skey[s & 1][0];
    float nx = sxyz[s & 1][0][0], ny = sxyz[s & 1][0][1], nz = sxyz[s & 1][0][2];
#pragma unroll
    for (int q = 1; q < NW; q++) {
      unsigned long long k2 = skey[s & 1][q];
      bool gt = k2 > best;                       // max d-bits, ties -> min gidx
      best = gt ? k2 : best;
      nx = gt ? sxyz[s & 1][q][0] : nx;
      ny = gt ? sxyz[s & 1][q][1] : ny;
      nz = gt ? sxyz[s & 1][q][2] : nz;
    }
    cx = nx; cy = ny; cz = nz;
    if (t == 0) { scb[(s + 1) * 3 + 0] = cx; scb[(s + 1) * 3 + 1] = cy;
                  scb[(s + 1) * 3 + 2] = cz; }
  }
  __syncthreads();
  for (int i = t; i < NSAMP * 3; i += NTH) cb[i] = scb[i];
}

// ---- fps2: one batch, NPTS=2048, 512 thr, PT=4 (2 v2f pairs), NSAMP=512 ----
__device__ void fps2_one(const float* __restrict__ p, float* __restrict__ cb) {
#pragma clang fp contract(off)
  constexpr int NTH = 512, PT = 4, NW = 8, NSAMP = 512;
  __shared__ unsigned long long skey2[2][NW];
  __shared__ float sxyz2[2][NW][3];
  __shared__ float scb2[NSAMP * 3];
  const int t = threadIdx.x, lane = t & 63, w = t >> 6;
  const float INF = __builtin_inff();
  v2f px0, px1, py0, py1, pz0, pz1, md0, md1;
  {
    int jb = t * PT;
    px0 = (v2f){p[(jb+0)*3+0], p[(jb+1)*3+0]};
    py0 = (v2f){p[(jb+0)*3+1], p[(jb+1)*3+1]};
    pz0 = (v2f){p[(jb+0)*3+2], p[(jb+1)*3+2]};
    px1 = (v2f){p[(jb+2)*3+0], p[(jb+3)*3+0]};
    py1 = (v2f){p[(jb+2)*3+1], p[(jb+3)*3+1]};
    pz1 = (v2f){p[(jb+2)*3+2], p[(jb+3)*3+2]};
    md0 = (v2f){INF, INF}; md1 = (v2f){INF, INF};
  }
  float cx = p[0], cy = p[1], cz = p[2];
  if (t == 0) { scb2[0] = cx; scb2[1] = cy; scb2[2] = cz; }
  for (int s = 0; s < NSAMP - 1; ++s) {
    v2f cxv = {cx, cx}, cyv = {cy, cy}, czv = {cz, cz};
    v2f bv2 = (v2f){-INF, -INF};
    DIST_PAIR(px0, py0, pz0, md0)
    DIST_PAIR(px1, py1, pz1, md1)
    float bv = fmaxf(bv2.x, bv2.y);
    int bi = 0;
    if (md1.y == bv) bi = 3;
    if (md1.x == bv) bi = 2;
    if (md0.y == bv) bi = 1;
    if (md0.x == bv) bi = 0;
    float wmax = wave_max_bcast(bv);
    unsigned long long ball = __ballot(bv == wmax);
    int fl = __ffsll((long long)ball) - 1;
    int ib = __builtin_amdgcn_readlane(bi, fl);
    int gidx = ((w << 6) + fl) * PT + ib;
    int kk = ib >> 1;
    v2f sx = px0, sy = py0, sz = pz0;
    if (kk == 1) { sx = px1; sy = py1; sz = pz1; }
    float wx = (ib & 1) ? sx.y : sx.x;
    float wy = (ib & 1) ? sy.y : sy.x;
    float wz = (ib & 1) ? sz.y : sz.x;
    wx = __int_as_float(__builtin_amdgcn_readlane(__float_as_int(wx), fl));
    wy = __int_as_float(__builtin_amdgcn_readlane(__float_as_int(wy), fl));
    wz = __int_as_float(__builtin_amdgcn_readlane(__float_as_int(wz), fl));
    if (lane == 0) {
      skey2[s & 1][w] = (((unsigned long long)(unsigned)__float_as_int(wmax)) << 32)
                        | (unsigned)(~gidx);
      sxyz2[s & 1][w][0] = wx; sxyz2[s & 1][w][1] = wy; sxyz2[s & 1][w][2] = wz;
    }
    __syncthreads();
    unsigned long long best = skey2[s & 1][0];
    float nx = sxyz2[s & 1][0][0], ny = sxyz2[s & 1][0][1], nz = sxyz2[s & 1][0][2];
#pragma unroll
    for (int q = 1; q < NW; q++) {
      unsigned long long k2 = skey2[s & 1][q];
      bool gt = k2 > best;
      best = gt ? k2 : best;
      nx = gt ? sxyz2[s & 1][q][0] : nx;
      ny = gt ? sxyz2[s & 1][q][1] : ny;
      nz = gt ? sxyz2[s & 1][q][2] : nz;
    }
    cx = nx; cy = ny; cz = nz;
    if (t == 0) { scb2[(s + 1) * 3 + 0] = cx; scb2[(s + 1) * 3 + 1] = cy;
                  scb2[(s + 1) * 3 + 2] = cz; }
  }
  __syncthreads();
  for (int i = t; i < NSAMP * 3; i += NTH) cb[i] = scb2[i];
}

// ---------------------------------------------------------------------------
// Ball query + exact 64 nearest within radius (one wave per center).
// WPB waves per block, LCAP candidate capacity per wave.
// ---------------------------------------------------------------------------
template<int NPTS, int SPB, int LCAP, int WPB>
__device__ void ballquery_body(int bb, const float* __restrict__ pts,
    const float* __restrict__ ctr, float rr,
    int* __restrict__ nbr, int* __restrict__ cnt_out) {
#pragma clang fp contract(off)
  constexpr int KREG = LCAP / 64;
  const int gw = bb * WPB + (threadIdx.x >> 6);
  const int lane = threadIdx.x & 63;
  const int b = gw / SPB;
  __shared__ unsigned long long list_[WPB][LCAP];
  unsigned long long* list = list_[threadIdx.x >> 6];
  const float* p = pts + (size_t)b * NPTS * 3;
  const float* c = ctr + (size_t)gw * 3;
  const float cx = c[0], cy = c[1], cz = c[2];
  const unsigned long long lmask = (1ull << lane) - 1ull;
  int cnt = 0;
  for (int j0 = 0; j0 < NPTS; j0 += 64) {
    int j = j0 + lane;
    float dx = p[j * 3 + 0] - cx, dy = p[j * 3 + 1] - cy, dz = p[j * 3 + 2] - cz;
    float d = (dx * dx + dy * dy) + dz * dz;
    bool in = (d <= rr);
    unsigned long long bal = __ballot(in);
    int pos = cnt + __popcll(bal & lmask);
    if (in && pos < LCAP)
      list[pos] = (((unsigned long long)__float_as_uint(d)) << 32) | (unsigned)j;
    cnt += __popcll(bal);
  }
  if (cnt > LCAP) cnt = LCAP;
  __syncthreads();
  int* nbrp = nbr + (size_t)gw * 64;
  const int nr = (cnt + 63) >> 6;
  unsigned long long key[KREG];
#pragma unroll
  for (int r = 0; r < KREG; r++) {
    int slot = r * 64 + lane;
    key[r] = (r < nr && slot < cnt) ? list[slot] : ~0ull;
  }
  if (cnt <= 64) {
    nbrp[lane] = (lane < cnt) ? (int)(unsigned)key[0] : 0;
    if (lane == 0) cnt_out[gw] = cnt;
    return;
  }
  // radix select on d2 bits (d2 < 2.0 -> bits 31:30 are 0)
  unsigned pref = 0; int cbase = 0;
  for (int bit = 29; bit >= 0; --bit) {
    int cc = 0;
#pragma unroll
    for (int r = 0; r < KREG; r++) if (r < nr) {
      unsigned db = (unsigned)(key[r] >> 32);
      cc += ((db >> bit) == (pref >> bit)) ? 1 : 0;
    }
    cc = wave_sum_bcast(cc);
    if (cbase + cc < 64) { cbase += cc; pref |= (1u << bit); }
  }
  int base = 0;
#pragma unroll
  for (int r = 0; r < KREG; r++) if (r < nr) {
    unsigned db = (unsigned)(key[r] >> 32);
    bool sel = db < pref;
    unsigned long long m = __ballot(sel);
    if (sel) nbrp[base + __popcll(m & lmask)] = (int)(unsigned)key[r];
    base += __popcll(m);
  }
  int need = 64 - base;
  for (int t2 = 0; t2 < need; ++t2) {
    unsigned besti = 0xffffffffu;
#pragma unroll
    for (int r = 0; r < KREG; r++) if (r < nr) {
      if ((unsigned)(key[r] >> 32) == pref) {
        unsigned v = (unsigned)key[r];
        besti = v < besti ? v : besti;
      }
    }
#pragma unroll
    for (int off = 32; off; off >>= 1) {
      unsigned o = __shfl_xor(besti, off, 64);
      besti = o < besti ? o : besti;
    }
    unsigned long long wk = (((unsigned long long)pref) << 32) | besti;
#pragma unroll
    for (int r = 0; r < KREG; r++) if (r < nr && key[r] == wk) key[r] = ~0ull;
    if (lane == 0) nbrp[base + t2] = (int)besti;
  }
  if (lane == 0) cnt_out[gw] = 64;
}

// ---- SA layer-1 split bodies ----------------------------------------------
__device__ void q1_body(int bb, const float* __restrict__ x,
    const float* __restrict__ pos, const float* __restrict__ w, float* __restrict__ q) {
  int gw = bb * 8 + (threadIdx.x >> 6), lane = threadIdx.x & 63;  // 512-thr blocks
  const float* xr = x + (size_t)gw * 3; const float* pr = pos + (size_t)gw * 3;
  float a = 0.f;
#pragma unroll
  for (int m = 0; m < 3; m++) a = fmaf(xr[m], w[m * 64 + lane], a);
#pragma unroll
  for (int m = 0; m < 3; m++) a = fmaf(pr[m], w[(3 + m) * 64 + lane], a);
  q[(size_t)gw * 64 + lane] = a;
}

__device__ void t1_body(int bb, const float* __restrict__ c1,
    const float* __restrict__ w, const float* __restrict__ b1, float* __restrict__ t) {
  int gw = bb * 8 + (threadIdx.x >> 6), lane = threadIdx.x & 63;  // 512-thr blocks
  const float* cr = c1 + (size_t)gw * 3;
  float a = b1[lane];
#pragma unroll
  for (int m = 0; m < 3; m++) a = fmaf(-cr[m], w[(3 + m) * 64 + lane], a);
  t[(size_t)gw * 64 + lane] = a;
}

__device__ void t2_body(int bb, const float* __restrict__ c2,
    const float* __restrict__ w, const float* __restrict__ b1, float* __restrict__ t) {
  int gw = (bb << 2) + (threadIdx.x >> 6), lane = threadIdx.x & 63;
  const float* cr = c2 + (size_t)gw * 3;
  float a0 = b1[lane], a1 = b1[64 + lane];
#pragma unroll
  for (int m = 0; m < 3; m++) {
    a0 = fmaf(-cr[m], w[(128 + m) * 128 + lane], a0);
    a1 = fmaf(-cr[m], w[(128 + m) * 128 + 64 + lane], a1);
  }
  t[(size_t)gw * 128 + lane] = a0;
  t[(size_t)gw * 128 + 64 + lane] = a1;
}

__device__ void concat3_body(int bb, const float* __restrict__ c2, float* __restrict__ xin3) {
  int row = bb * 256 + threadIdx.x;
  if (row < NBATCH * 512) {
    float* o = xin3 + (size_t)row * 272 + 256;
    const float* c = c2 + (size_t)row * 3;
    o[0] = c[0]; o[1] = c[1]; o[2] = c[2];
#pragma unroll
    for (int i = 3; i < 16; i++) o[i] = 0.f;
  }
}

// ---------------------------------------------------------------------------
// Per-center: h1[k] = relu(q[nbr_k] + t_s); h2 = h1 @ W2 + b2; out = max_k h2.
// ---------------------------------------------------------------------------
template<int CIN, int COUT, int OSTR, int NPB, int SPB>
__device__ void sa_pool_body(int bb, const float* __restrict__ q,
    const float* __restrict__ t, const int* __restrict__ nbr, const int* __restrict__ cnt,
    const float* __restrict__ w2, const float* __restrict__ b2, float* __restrict__ out) {
  int gw = (bb << 2) + (threadIdx.x >> 6), lane = threadIdx.x & 63;
  int b = gw / SPB;
  int nk = nbr[(size_t)gw * 64 + lane];
  int c = cnt[gw];
  const float* qr = q + ((size_t)b * NPB + nk) * CIN;
  const float* tr = t + (size_t)gw * CIN;
  float h[CIN];
#pragma unroll
  for (int i = 0; i < CIN; i += 4) {
    float4 v = *(const float4*)(qr + i);
    h[i]     = fmaxf(v.x + tr[i], 0.f);
    h[i + 1] = fmaxf(v.y + tr[i + 1], 0.f);
    h[i + 2] = fmaxf(v.z + tr[i + 2], 0.f);
    h[i + 3] = fmaxf(v.w + tr[i + 3], 0.f);
  }
  bool valid = lane < c;
  float* op = out + (size_t)gw * OSTR;
#pragma unroll 1
  for (int nc = 0; nc < COUT; nc += 16) {
    float acc[16];
#pragma unroll
    for (int u = 0; u < 16; u++) acc[u] = b2[nc + u];
#pragma unroll
    for (int i = 0; i < CIN; i++) {
      const float* wr = w2 + (size_t)i * COUT + nc;
#pragma unroll
      for (int u = 0; u < 16; u++) acc[u] = fmaf(h[i], wr[u], acc[u]);
    }
#pragma unroll
    for (int u = 0; u < 16; u++) {
      float v = valid ? acc[u] : -__builtin_inff();
#pragma unroll
      for (int off = 32; off; off >>= 1) v = fmaxf(v, __shfl_xor(v, off, 64));
      acc[u] = v;
    }
    if (lane == 0) {
#pragma unroll
      for (int u = 0; u < 16; u += 4)
        *(float4*)(op + nc + u) = make_float4(acc[u], acc[u + 1], acc[u + 2], acc[u + 3]);
    }
  }
}

// ---- fused kernels ---------------------------------------------------------
__global__ __launch_bounds__(512, 2) void fuse1_kernel(const float* __restrict__ pos,
    const float* __restrict__ x, const float* __restrict__ w11,
    float* __restrict__ c1, float* __restrict__ q1) {
  int bid = blockIdx.x;
  if (bid < 8)
    fps1_one(pos + (size_t)bid * 4096 * 3, c1 + (size_t)bid * 2048 * 3);
  else
    q1_body(bid - 8, x, pos, w11, q1);
}

__global__ __launch_bounds__(512, 2) void fuse2_kernel(const float* __restrict__ pos,
    const float* __restrict__ c1, const float* __restrict__ w11, const float* __restrict__ b11,
    float* __restrict__ c2, int* __restrict__ nbr1, int* __restrict__ cnt1,
    float* __restrict__ t1buf, float rr1) {
  int bid = blockIdx.x;
  if (bid < 8)
    fps2_one(c1 + (size_t)bid * 2048 * 3, c2 + (size_t)bid * 512 * 3);
  else if (bid < 8 + 2048)
    ballquery_body<4096, 2048, 512, 8>(bid - 8, pos, c1, rr1, nbr1, cnt1);
  else
    t1_body(bid - (8 + 2048), c1, w11, b11, t1buf);
}

__global__ __launch_bounds__(256) void fuse3_kernel(const float* __restrict__ q1buf,
    const float* __restrict__ t1buf, const int* __restrict__ nbr1, const int* __restrict__ cnt1,
    const float* __restrict__ w12, const float* __restrict__ b12, float* __restrict__ x1,
    const float* __restrict__ c1, const float* __restrict__ c2, float rr2,
    int* __restrict__ nbr2, int* __restrict__ cnt2,
    const float* __restrict__ w21, const float* __restrict__ b21, float* __restrict__ t2buf,
    float* __restrict__ xin3) {
  int bid = blockIdx.x;
  if (bid < 4096)
    sa_pool_body<64, 128, 128, 4096, 2048>(bid, q1buf, t1buf, nbr1, cnt1, w12, b12, x1);
  else if (bid < 4096 + 1024)
    ballquery_body<2048, 512, 1024, 4>(bid - 4096, c1, c2, rr2, nbr2, cnt2);
  else if (bid < 4096 + 1024 + 1024)
    t2_body(bid - (4096 + 1024), c2, w21, b21, t2buf);
  else
    concat3_body(bid - (4096 + 1024 + 1024), c2, xin3);
}

// SA2 layer-1 q: q2[j] = [x1_j,p1_j] @ W1 (131->128)
__global__ __launch_bounds__(256) void q2_kernel(const float* __restrict__ x1,
    const float* __restrict__ p1, const float* __restrict__ w, float* __restrict__ q2) {
  int gw = (blockIdx.x << 2) + (threadIdx.x >> 6), lane = threadIdx.x & 63;
  const float* xr = x1 + (size_t)gw * 128; const float* pr = p1 + (size_t)gw * 3;
  float a0 = 0.f, a1 = 0.f;
#pragma unroll 8
  for (int m = 0; m < 128; m++) {
    float v = xr[m];
    a0 = fmaf(v, w[m * 128 + lane], a0);
    a1 = fmaf(v, w[m * 128 + 64 + lane], a1);
  }
#pragma unroll
  for (int m = 0; m < 3; m++) {
    float v = pr[m];
    a0 = fmaf(v, w[(128 + m) * 128 + lane], a0);
    a1 = fmaf(v, w[(128 + m) * 128 + 64 + lane], a1);
  }
  q2[(size_t)gw * 128 + lane] = a0;
  q2[(size_t)gw * 128 + 64 + lane] = a1;
}

__global__ __launch_bounds__(256) void sa_pool2_kernel(const float* __restrict__ q,
    const float* __restrict__ t, const int* __restrict__ nbr, const int* __restrict__ cnt,
    const float* __restrict__ w2, const float* __restrict__ b2, float* __restrict__ out) {
  sa_pool_body<128, 256, 272, 2048, 512>(blockIdx.x, q, t, nbr, cnt, w2, b2, out);
}

// ---------------------------------------------------------------------------
// Tiled fp32 GEMM, 64x64 block tile, 256 threads (4x4 per thread), K-step 16.
// ---------------------------------------------------------------------------
template<int K, int KP, int N, int AST, bool RELU>
__global__ __launch_bounds__(256) void gemm64(const float* __restrict__ A,
    const float* __restrict__ W, const float* __restrict__ bias, float* __restrict__ C) {
  constexpr int NT = N / 64;
  const int bid = blockIdx.x, tid = threadIdx.x;
  const int tm = bid / NT, tn = bid % NT;
  __shared__ __align__(16) float As[16][68];
  __shared__ __align__(16) float Ws[16][68];
  const int arow = tid >> 2, acol = (tid & 3) << 2;
  const int wrow = tid >> 4, wcol = (tid & 15) << 2;
  const int ty = tid >> 4, tx = tid & 15;
  const float* Ap = A + (size_t)(tm * 64 + arow) * AST + acol;
  const float* Wp = W + (size_t)tn * 64 + wcol;
  float acc[4][4] = {};
  for (int k0 = 0; k0 < KP; k0 += 16) {
    float4 av = *(const float4*)(Ap + k0);
    As[acol + 0][arow] = av.x; As[acol + 1][arow] = av.y;
    As[acol + 2][arow] = av.z; As[acol + 3][arow] = av.w;
    int krow = k0 + wrow;
    float4 wv = make_float4(0.f, 0.f, 0.f, 0.f);
    if (krow < K) wv = *(const float4*)(Wp + (size_t)krow * N);
    *(float4*)(&Ws[wrow][wcol]) = wv;
    __syncthreads();
#pragma unroll
    for (int kk = 0; kk < 16; kk++) {
      float4 a4 = *(const float4*)(&As[kk][ty << 2]);
      float4 b4 = *(const float4*)(&Ws[kk][tx << 2]);
      float aa[4] = {a4.x, a4.y, a4.z, a4.w};
      float bb[4] = {b4.x, b4.y, b4.z, b4.w};
#pragma unroll
      for (int mm = 0; mm < 4; mm++)
#pragma unroll
        for (int nn = 0; nn < 4; nn++) acc[mm][nn] = fmaf(aa[mm], bb[nn], acc[mm][nn]);
    }
    __syncthreads();
  }
  const int m0 = tm * 64 + (ty << 2), n0 = tn * 64 + (tx << 2);
#pragma unroll
  for (int mm = 0; mm < 4; mm++) {
    float4 o;
    o.x = acc[mm][0] + bias[n0 + 0];
    o.y = acc[mm][1] + bias[n0 + 1];
    o.z = acc[mm][2] + bias[n0 + 2];
    o.w = acc[mm][3] + bias[n0 + 3];
    if (RELU) { o.x = fmaxf(o.x, 0.f); o.y = fmaxf(o.y, 0.f);
                o.z = fmaxf(o.z, 0.f); o.w = fmaxf(o.w, 0.f); }
    *(float4*)(C + (size_t)(m0 + mm) * N + n0) = o;
  }
}

// global max over 512 points per batch: [8,512,1024] -> [8,1024]
__global__ void gmax_kernel(const float* __restrict__ h, float* __restrict__ g) {
  int n = blockIdx.x * 256 + threadIdx.x;          // 8192 outputs
  int b = n >> 10, col = n & 1023;
  const float* p = h + ((size_t)b * 512) * 1024 + col;
  float m = -__builtin_inff();
  for (int j = 0; j < 512; j++) m = fmaxf(m, p[(size_t)j * 1024]);
  g[n] = m;
}

// head MLP: 1024 ->512 relu ->256 relu ->40. One block per batch.
__global__ __launch_bounds__(256) void head_kernel(const float* __restrict__ g,
    const float* __restrict__ w1, const float* __restrict__ b1,
    const float* __restrict__ w2, const float* __restrict__ b2,
    const float* __restrict__ w3, const float* __restrict__ b3,
    float* __restrict__ out) {
  int b = blockIdx.x, t = threadIdx.x;
  __shared__ float s1[1024];
  __shared__ float s2[512];
  *(float4*)(s1 + t * 4) = *(const float4*)(g + (size_t)b * 1024 + t * 4);
  __syncthreads();
  {
    float a0 = b1[t], a1 = b1[t + 256];
    for (int i = 0; i < 1024; i++) {
      float v = s1[i];
      a0 = fmaf(v, w1[(size_t)i * 512 + t], a0);
      a1 = fmaf(v, w1[(size_t)i * 512 + t + 256], a1);
    }
    s2[t] = fmaxf(a0, 0.f); s2[t + 256] = fmaxf(a1, 0.f);
  }
  __syncthreads();
  {
    float a = b2[t];
    for (int i = 0; i < 512; i++) a = fmaf(s2[i], w2[(size_t)i * 256 + t], a);
    s1[t] = fmaxf(a, 0.f);
  }
  __syncthreads();
  if (t < 40) {
    float a = b3[t];
    for (int i = 0; i < 256; i++) a = fmaf(s1[i], w3[(size_t)i * 40 + t], a);
    out[(size_t)b * 40 + t] = a;
  }
}

// ===========================================================================
extern "C" void kernel_launch(void* const* d_in, const int* in_sizes, int n_in,
                              void* d_out, int out_size, void* d_ws, size_t ws_size,
                              hipStream_t stream) {
  const float* x   = (const float*)d_in[0];
  const float* pos = (const float*)d_in[1];
  const float* w11 = (const float*)d_in[2];  const float* b11 = (const float*)d_in[3];
  const float* w12 = (const float*)d_in[4];  const float* b12 = (const float*)d_in[5];
  const float* w21 = (const float*)d_in[6];  const float* b21 = (const float*)d_in[7];
  const float* w22 = (const float*)d_in[8];  const float* b22 = (const float*)d_in[9];
  const float* w31 = (const float*)d_in[10]; const float* b31 = (const float*)d_in[11];
  const float* w32 = (const float*)d_in[12]; const float* b32 = (const float*)d_in[13];
  const float* w33 = (const float*)d_in[14]; const float* b33 = (const float*)d_in[15];
  const float* hw1 = (const float*)d_in[16]; const float* hb1 = (const float*)d_in[17];
  const float* hw2 = (const float*)d_in[18]; const float* hb2 = (const float*)d_in[19];
  const float* hw3 = (const float*)d_in[20]; const float* hb3 = (const float*)d_in[21];
  float* out = (float*)d_out;

  // workspace layout (aliased by liveness); total ~41.7 MB
  char* wsb = (char*)d_ws;
  int*   cnt1 = (int*)(wsb + 81920);       // 64K
  int*   cnt2 = (int*)(wsb + 147456);      // 16K
  float* c1   = (float*)(wsb + 163840);    // 192K  (= p1)
  float* c2   = (float*)(wsb + 360448);    // 48K   (= p2)
  float* g    = (float*)(wsb + 409600);    // 32K
  char* big = wsb + 524288;
  int*   nbr1 = (int*)(big + 0);           // 4M   } dead after sa_pool1
  float* q1   = (float*)(big + 4194304);   // 8M   } -> h3c aliases (16M)
  float* t1   = (float*)(big + 12582912);  // 4M   }
  float* h3c  = (float*)(big + 0);
  float* x1   = (float*)(big + 16777216);  // 8M   } dead after q2/sa_pool2
  int*   nbr2 = (int*)(big + 25165824);    // 1M   } -> h3b aliases (8M)
  float* h3b  = (float*)(big + 16777216);
  float* q2   = (float*)(big + 26214400);  // 8M   -> h3a aliases (4M)
  float* h3a  = (float*)(big + 26214400);
  float* t2   = (float*)(big + 34603008);  // 2M
  float* xin3 = (float*)(big + 36700160);  // 4.45M  [8*512, 272]

  const float RR1 = (float)(0.2 * 0.2);    // match python-traced f32 constants
  const float RR2 = (float)(0.4 * 0.4);

  // ---- stage 1: fps1 (8 blocks, 1 batch each) || q1 ----
  fuse1_kernel<<<8 + 4096, 512, 0, stream>>>(pos, x, w11, c1, q1);
  // ---- stage 2: fps2 (8 blocks) || ballquery1 || t1 ----
  fuse2_kernel<<<8 + 2048 + 2048, 512, 0, stream>>>(pos, c1, w11, b11,
                                                    c2, nbr1, cnt1, t1, RR1);
  // ---- stage 3: sa_pool1 || ballquery2 || t2 || concat3 ----
  fuse3_kernel<<<4096 + 1024 + 1024 + 16, 256, 0, stream>>>(q1, t1, nbr1, cnt1,
      w12, b12, x1, c1, c2, RR2, nbr2, cnt2, w21, b21, t2, xin3);
  // ---- stage 4+: SA2 finish, global SA, head ----
  q2_kernel<<<4096, 256, 0, stream>>>(x1, c1, w21, q2);
  sa_pool2_kernel<<<1024, 256, 0, stream>>>(q2, t2, nbr2, cnt2, w22, b22, xin3);
  gemm64<259, 272, 256, 272, true ><<<256,  256, 0, stream>>>(xin3, w31, b31, h3a);
  gemm64<256, 256, 512, 256, true ><<<512,  256, 0, stream>>>(h3a,  w32, b32, h3b);
  gemm64<512, 512, 1024, 512, false><<<1024, 256, 0, stream>>>(h3b, w33, b33, h3c);
  gmax_kernel<<<32, 256, 0, stream>>>(h3c, g);
  head_kernel<<<NBATCH, 256, 0, stream>>>(g, hw1, hb1, hw2, hb2, hw3, hb3, out);

  (void)in_sizes; (void)n_in; (void)out_size; (void)ws_size;
}

// Round 10
// 3615.586 us; speedup vs baseline: 2.3608x; 1.1384x over previous
//
#include <hip/hip_runtime.h>

// ============================================================================
// PointNet++ (8 batches, N=4096) forward on MI355X — full pipeline, fp32.
// Round 10: FPS = 256 thr (1 wave/SIMD -> no issue contention), PT=16 scalar
// register arrays (r4/r7-proven codegen), xyz-carry (r8-validated), and the
// explicit allocator attributes amdgpu_flat_work_group_size(256,256) +
// amdgpu_waves_per_eu(1,2) to stop the occupancy heuristic from capping
// VGPRs (r5/r8/r9 all lost the state to spill/reload under the default cap).
// Fusion graph unchanged: fuse1 = fps1||q1, fuse2 = fps2||bq1||t1,
// fuse3 = sa_pool1||bq2||t2||concat3.
// ============================================================================

constexpr int NBATCH = 8;

// ---- DPP wave64 reduction helpers -----------------------------------------
template<int CTRL>
__device__ __forceinline__ float dpp_max_step(float v) {
  int o = __builtin_amdgcn_update_dpp(__float_as_int(v), __float_as_int(v),
                                      CTRL, 0xf, 0xf, false);  // invalid -> old(=v)
  return fmaxf(v, __int_as_float(o));
}
__device__ __forceinline__ float wave_max_bcast(float v) {
  v = dpp_max_step<0x111>(v);  // row_shr:1
  v = dpp_max_step<0x112>(v);  // row_shr:2
  v = dpp_max_step<0x114>(v);  // row_shr:4
  v = dpp_max_step<0x118>(v);  // row_shr:8
  v = dpp_max_step<0x142>(v);  // row_bcast:15
  v = dpp_max_step<0x143>(v);  // row_bcast:31
  return __int_as_float(__builtin_amdgcn_readlane(__float_as_int(v), 63));
}
template<int CTRL>
__device__ __forceinline__ int dpp_add_step(int v) {
  int o = __builtin_amdgcn_update_dpp(0, v, CTRL, 0xf, 0xf, true);  // invalid -> 0
  return v + o;
}
__device__ __forceinline__ int wave_sum_bcast(int v) {
  v = dpp_add_step<0x111>(v);
  v = dpp_add_step<0x112>(v);
  v = dpp_add_step<0x114>(v);
  v = dpp_add_step<0x118>(v);
  v = dpp_add_step<0x142>(v);
  v = dpp_add_step<0x143>(v);
  return __builtin_amdgcn_readlane(v, 63);
}

// ---------------------------------------------------------------------------
// fps1: one batch, NPTS=4096, 256 thr (4 waves, 1/SIMD), PT=16 scalar arrays.
// Per step: dist+min update; tree max; descending equality scan (-> lowest
// slot, == first-occurrence argmax, r8-validated); DPP wave max; ballot
// lowest-lane; winner xyz via wave-uniform unrolled select + readlane;
// lane0 {key,xyz} -> LDS; ONE barrier; 4-way cndmask-carry merge.
// Centers accumulate in LDS scb; coalesced dump at the end.
// ---------------------------------------------------------------------------
__device__ void fps1_one(const float* __restrict__ p, float* __restrict__ cb) {
#pragma clang fp contract(off)
  constexpr int NTH = 256, PT = 16, NW = 4, NSAMP = 2048;
  __shared__ unsigned long long skey[2][NW];
  __shared__ float sxyz[2][NW][3];
  __shared__ float scb[NSAMP * 3];
  const int t = threadIdx.x, lane = t & 63, w = t >> 6;
  const float INF = __builtin_inff();
  float px[PT], py[PT], pz[PT], md[PT];
#pragma unroll
  for (int i = 0; i < PT; i++) {
    int j = t * PT + i;
    px[i] = p[j * 3 + 0]; py[i] = p[j * 3 + 1]; pz[i] = p[j * 3 + 2];
    md[i] = INF;
  }
  float cx = p[0], cy = p[1], cz = p[2];
  if (t == 0) { scb[0] = cx; scb[1] = cy; scb[2] = cz; }
  for (int s = 0; s < NSAMP - 1; ++s) {
#pragma unroll
    for (int i = 0; i < PT; i++) {
      float dx = px[i] - cx, dy = py[i] - cy, dz = pz[i] - cz;
      float d = (dx * dx + dy * dy) + dz * dz;   // contract off: match XLA order
      md[i] = fminf(md[i], d);
    }
    // tree max (depth 4) then descending equality scan -> lowest slot
    float m8[8];
#pragma unroll
    for (int i = 0; i < 8; i++) m8[i] = fmaxf(md[i], md[i + 8]);
    float m4[4];
#pragma unroll
    for (int i = 0; i < 4; i++) m4[i] = fmaxf(m8[i], m8[i + 4]);
    float bv = fmaxf(fmaxf(m4[0], m4[1]), fmaxf(m4[2], m4[3]));
    int bi = 0;
#pragma unroll
    for (int i = PT - 1; i >= 1; --i) if (md[i] == bv) bi = i;
    float wmax = wave_max_bcast(bv);
    unsigned long long ball = __ballot(bv == wmax);
    int fl = __ffsll((long long)ball) - 1;       // lowest lane = lowest index
    int ib = __builtin_amdgcn_readlane(bi, fl);  // wave-uniform slot
    int gidx = ((w << 6) + fl) * PT + ib;
    float sx = px[0], sy = py[0], sz = pz[0];
#pragma unroll
    for (int k = 1; k < PT; k++)
      if (ib == k) { sx = px[k]; sy = py[k]; sz = pz[k]; }
    sx = __int_as_float(__builtin_amdgcn_readlane(__float_as_int(sx), fl));
    sy = __int_as_float(__builtin_amdgcn_readlane(__float_as_int(sy), fl));
    sz = __int_as_float(__builtin_amdgcn_readlane(__float_as_int(sz), fl));
    if (lane == 0) {
      skey[s & 1][w] = (((unsigned long long)(unsigned)__float_as_int(wmax)) << 32)
                       | (unsigned)(~gidx);
      sxyz[s & 1][w][0] = sx; sxyz[s & 1][w][1] = sy; sxyz[s & 1][w][2] = sz;
    }
    __syncthreads();
    unsigned long long best = skey[s & 1][0];
    float nx = sxyz[s & 1][0][0], ny = sxyz[s & 1][0][1], nz = sxyz[s & 1][0][2];
#pragma unroll
    for (int q = 1; q < NW; q++) {
      unsigned long long k2 = skey[s & 1][q];
      bool gt = k2 > best;                       // max d-bits, ties -> min gidx
      best = gt ? k2 : best;
      nx = gt ? sxyz[s & 1][q][0] : nx;
      ny = gt ? sxyz[s & 1][q][1] : ny;
      nz = gt ? sxyz[s & 1][q][2] : nz;
    }
    cx = nx; cy = ny; cz = nz;
    if (t == 0) { scb[(s + 1) * 3 + 0] = cx; scb[(s + 1) * 3 + 1] = cy;
                  scb[(s + 1) * 3 + 2] = cz; }
  }
  __syncthreads();
  for (int i = t; i < NSAMP * 3; i += NTH) cb[i] = scb[i];
}

// ---- fps2: one batch, NPTS=2048, 256 thr, PT=8 scalar arrays, NSAMP=512 ----
__device__ void fps2_one(const float* __restrict__ p, float* __restrict__ cb) {
#pragma clang fp contract(off)
  constexpr int NTH = 256, PT = 8, NW = 4, NSAMP = 512;
  __shared__ unsigned long long skey2[2][NW];
  __shared__ float sxyz2[2][NW][3];
  __shared__ float scb2[NSAMP * 3];
  const int t = threadIdx.x, lane = t & 63, w = t >> 6;
  const float INF = __builtin_inff();
  float px[PT], py[PT], pz[PT], md[PT];
#pragma unroll
  for (int i = 0; i < PT; i++) {
    int j = t * PT + i;
    px[i] = p[j * 3 + 0]; py[i] = p[j * 3 + 1]; pz[i] = p[j * 3 + 2];
    md[i] = INF;
  }
  float cx = p[0], cy = p[1], cz = p[2];
  if (t == 0) { scb2[0] = cx; scb2[1] = cy; scb2[2] = cz; }
  for (int s = 0; s < NSAMP - 1; ++s) {
#pragma unroll
    for (int i = 0; i < PT; i++) {
      float dx = px[i] - cx, dy = py[i] - cy, dz = pz[i] - cz;
      float d = (dx * dx + dy * dy) + dz * dz;
      md[i] = fminf(md[i], d);
    }
    float m4[4];
#pragma unroll
    for (int i = 0; i < 4; i++) m4[i] = fmaxf(md[i], md[i + 4]);
    float bv = fmaxf(fmaxf(m4[0], m4[1]), fmaxf(m4[2], m4[3]));
    int bi = 0;
#pragma unroll
    for (int i = PT - 1; i >= 1; --i) if (md[i] == bv) bi = i;
    float wmax = wave_max_bcast(bv);
    unsigned long long ball = __ballot(bv == wmax);
    int fl = __ffsll((long long)ball) - 1;
    int ib = __builtin_amdgcn_readlane(bi, fl);
    int gidx = ((w << 6) + fl) * PT + ib;
    float sx = px[0], sy = py[0], sz = pz[0];
#pragma unroll
    for (int k = 1; k < PT; k++)
      if (ib == k) { sx = px[k]; sy = py[k]; sz = pz[k]; }
    sx = __int_as_float(__builtin_amdgcn_readlane(__float_as_int(sx), fl));
    sy = __int_as_float(__builtin_amdgcn_readlane(__float_as_int(sy), fl));
    sz = __int_as_float(__builtin_amdgcn_readlane(__float_as_int(sz), fl));
    if (lane == 0) {
      skey2[s & 1][w] = (((unsigned long long)(unsigned)__float_as_int(wmax)) << 32)
                        | (unsigned)(~gidx);
      sxyz2[s & 1][w][0] = sx; sxyz2[s & 1][w][1] = sy; sxyz2[s & 1][w][2] = sz;
    }
    __syncthreads();
    unsigned long long best = skey2[s & 1][0];
    float nx = sxyz2[s & 1][0][0], ny = sxyz2[s & 1][0][1], nz = sxyz2[s & 1][0][2];
#pragma unroll
    for (int q = 1; q < NW; q++) {
      unsigned long long k2 = skey2[s & 1][q];
      bool gt = k2 > best;
      best = gt ? k2 : best;
      nx = gt ? sxyz2[s & 1][q][0] : nx;
      ny = gt ? sxyz2[s & 1][q][1] : ny;
      nz = gt ? sxyz2[s & 1][q][2] : nz;
    }
    cx = nx; cy = ny; cz = nz;
    if (t == 0) { scb2[(s + 1) * 3 + 0] = cx; scb2[(s + 1) * 3 + 1] = cy;
                  scb2[(s + 1) * 3 + 2] = cz; }
  }
  __syncthreads();
  for (int i = t; i < NSAMP * 3; i += NTH) cb[i] = scb2[i];
}

// ---------------------------------------------------------------------------
// Ball query + exact 64 nearest within radius (one wave per center).
// WPB waves per block, LCAP candidate capacity per wave.
// ---------------------------------------------------------------------------
template<int NPTS, int SPB, int LCAP, int WPB>
__device__ void ballquery_body(int bb, const float* __restrict__ pts,
    const float* __restrict__ ctr, float rr,
    int* __restrict__ nbr, int* __restrict__ cnt_out) {
#pragma clang fp contract(off)
  constexpr int KREG = LCAP / 64;
  const int gw = bb * WPB + (threadIdx.x >> 6);
  const int lane = threadIdx.x & 63;
  const int b = gw / SPB;
  __shared__ unsigned long long list_[WPB][LCAP];
  unsigned long long* list = list_[threadIdx.x >> 6];
  const float* p = pts + (size_t)b * NPTS * 3;
  const float* c = ctr + (size_t)gw * 3;
  const float cx = c[0], cy = c[1], cz = c[2];
  const unsigned long long lmask = (1ull << lane) - 1ull;
  int cnt = 0;
  for (int j0 = 0; j0 < NPTS; j0 += 64) {
    int j = j0 + lane;
    float dx = p[j * 3 + 0] - cx, dy = p[j * 3 + 1] - cy, dz = p[j * 3 + 2] - cz;
    float d = (dx * dx + dy * dy) + dz * dz;
    bool in = (d <= rr);
    unsigned long long bal = __ballot(in);
    int pos = cnt + __popcll(bal & lmask);
    if (in && pos < LCAP)
      list[pos] = (((unsigned long long)__float_as_uint(d)) << 32) | (unsigned)j;
    cnt += __popcll(bal);
  }
  if (cnt > LCAP) cnt = LCAP;
  __syncthreads();
  int* nbrp = nbr + (size_t)gw * 64;
  const int nr = (cnt + 63) >> 6;
  unsigned long long key[KREG];
#pragma unroll
  for (int r = 0; r < KREG; r++) {
    int slot = r * 64 + lane;
    key[r] = (r < nr && slot < cnt) ? list[slot] : ~0ull;
  }
  if (cnt <= 64) {
    nbrp[lane] = (lane < cnt) ? (int)(unsigned)key[0] : 0;
    if (lane == 0) cnt_out[gw] = cnt;
    return;
  }
  // radix select on d2 bits (d2 < 2.0 -> bits 31:30 are 0)
  unsigned pref = 0; int cbase = 0;
  for (int bit = 29; bit >= 0; --bit) {
    int cc = 0;
#pragma unroll
    for (int r = 0; r < KREG; r++) if (r < nr) {
      unsigned db = (unsigned)(key[r] >> 32);
      cc += ((db >> bit) == (pref >> bit)) ? 1 : 0;
    }
    cc = wave_sum_bcast(cc);
    if (cbase + cc < 64) { cbase += cc; pref |= (1u << bit); }
  }
  int base = 0;
#pragma unroll
  for (int r = 0; r < KREG; r++) if (r < nr) {
    unsigned db = (unsigned)(key[r] >> 32);
    bool sel = db < pref;
    unsigned long long m = __ballot(sel);
    if (sel) nbrp[base + __popcll(m & lmask)] = (int)(unsigned)key[r];
    base += __popcll(m);
  }
  int need = 64 - base;
  for (int t2 = 0; t2 < need; ++t2) {
    unsigned besti = 0xffffffffu;
#pragma unroll
    for (int r = 0; r < KREG; r++) if (r < nr) {
      if ((unsigned)(key[r] >> 32) == pref) {
        unsigned v = (unsigned)key[r];
        besti = v < besti ? v : besti;
      }
    }
#pragma unroll
    for (int off = 32; off; off >>= 1) {
      unsigned o = __shfl_xor(besti, off, 64);
      besti = o < besti ? o : besti;
    }
    unsigned long long wk = (((unsigned long long)pref) << 32) | besti;
#pragma unroll
    for (int r = 0; r < KREG; r++) if (r < nr && key[r] == wk) key[r] = ~0ull;
    if (lane == 0) nbrp[base + t2] = (int)besti;
  }
  if (lane == 0) cnt_out[gw] = 64;
}

// ---- SA layer-1 split bodies (256-thr blocks: 4 waves each) ----------------
__device__ void q1_body(int bb, const float* __restrict__ x,
    const float* __restrict__ pos, const float* __restrict__ w, float* __restrict__ q) {
  int gw = (bb << 2) + (threadIdx.x >> 6), lane = threadIdx.x & 63;
  const float* xr = x + (size_t)gw * 3; const float* pr = pos + (size_t)gw * 3;
  float a = 0.f;
#pragma unroll
  for (int m = 0; m < 3; m++) a = fmaf(xr[m], w[m * 64 + lane], a);
#pragma unroll
  for (int m = 0; m < 3; m++) a = fmaf(pr[m], w[(3 + m) * 64 + lane], a);
  q[(size_t)gw * 64 + lane] = a;
}

__device__ void t1_body(int bb, const float* __restrict__ c1,
    const float* __restrict__ w, const float* __restrict__ b1, float* __restrict__ t) {
  int gw = (bb << 2) + (threadIdx.x >> 6), lane = threadIdx.x & 63;
  const float* cr = c1 + (size_t)gw * 3;
  float a = b1[lane];
#pragma unroll
  for (int m = 0; m < 3; m++) a = fmaf(-cr[m], w[(3 + m) * 64 + lane], a);
  t[(size_t)gw * 64 + lane] = a;
}

__device__ void t2_body(int bb, const float* __restrict__ c2,
    const float* __restrict__ w, const float* __restrict__ b1, float* __restrict__ t) {
  int gw = (bb << 2) + (threadIdx.x >> 6), lane = threadIdx.x & 63;
  const float* cr = c2 + (size_t)gw * 3;
  float a0 = b1[lane], a1 = b1[64 + lane];
#pragma unroll
  for (int m = 0; m < 3; m++) {
    a0 = fmaf(-cr[m], w[(128 + m) * 128 + lane], a0);
    a1 = fmaf(-cr[m], w[(128 + m) * 128 + 64 + lane], a1);
  }
  t[(size_t)gw * 128 + lane] = a0;
  t[(size_t)gw * 128 + 64 + lane] = a1;
}

__device__ void concat3_body(int bb, const float* __restrict__ c2, float* __restrict__ xin3) {
  int row = bb * 256 + threadIdx.x;
  if (row < NBATCH * 512) {
    float* o = xin3 + (size_t)row * 272 + 256;
    const float* c = c2 + (size_t)row * 3;
    o[0] = c[0]; o[1] = c[1]; o[2] = c[2];
#pragma unroll
    for (int i = 3; i < 16; i++) o[i] = 0.f;
  }
}

// ---------------------------------------------------------------------------
// Per-center: h1[k] = relu(q[nbr_k] + t_s); h2 = h1 @ W2 + b2; out = max_k h2.
// ---------------------------------------------------------------------------
template<int CIN, int COUT, int OSTR, int NPB, int SPB>
__device__ void sa_pool_body(int bb, const float* __restrict__ q,
    const float* __restrict__ t, const int* __restrict__ nbr, const int* __restrict__ cnt,
    const float* __restrict__ w2, const float* __restrict__ b2, float* __restrict__ out) {
  int gw = (bb << 2) + (threadIdx.x >> 6), lane = threadIdx.x & 63;
  int b = gw / SPB;
  int nk = nbr[(size_t)gw * 64 + lane];
  int c = cnt[gw];
  const float* qr = q + ((size_t)b * NPB + nk) * CIN;
  const float* tr = t + (size_t)gw * CIN;
  float h[CIN];
#pragma unroll
  for (int i = 0; i < CIN; i += 4) {
    float4 v = *(const float4*)(qr + i);
    h[i]     = fmaxf(v.x + tr[i], 0.f);
    h[i + 1] = fmaxf(v.y + tr[i + 1], 0.f);
    h[i + 2] = fmaxf(v.z + tr[i + 2], 0.f);
    h[i + 3] = fmaxf(v.w + tr[i + 3], 0.f);
  }
  bool valid = lane < c;
  float* op = out + (size_t)gw * OSTR;
#pragma unroll 1
  for (int nc = 0; nc < COUT; nc += 16) {
    float acc[16];
#pragma unroll
    for (int u = 0; u < 16; u++) acc[u] = b2[nc + u];
#pragma unroll
    for (int i = 0; i < CIN; i++) {
      const float* wr = w2 + (size_t)i * COUT + nc;
#pragma unroll
      for (int u = 0; u < 16; u++) acc[u] = fmaf(h[i], wr[u], acc[u]);
    }
#pragma unroll
    for (int u = 0; u < 16; u++) {
      float v = valid ? acc[u] : -__builtin_inff();
#pragma unroll
      for (int off = 32; off; off >>= 1) v = fmaxf(v, __shfl_xor(v, off, 64));
      acc[u] = v;
    }
    if (lane == 0) {
#pragma unroll
      for (int u = 0; u < 16; u += 4)
        *(float4*)(op + nc + u) = make_float4(acc[u], acc[u + 1], acc[u + 2], acc[u + 3]);
    }
  }
}

// ---- fused kernels ---------------------------------------------------------
__global__ __attribute__((amdgpu_flat_work_group_size(256, 256),
                          amdgpu_waves_per_eu(1, 2)))
void fuse1_kernel(const float* __restrict__ pos,
    const float* __restrict__ x, const float* __restrict__ w11,
    float* __restrict__ c1, float* __restrict__ q1) {
  int bid = blockIdx.x;
  if (bid < 8)
    fps1_one(pos + (size_t)bid * 4096 * 3, c1 + (size_t)bid * 2048 * 3);
  else
    q1_body(bid - 8, x, pos, w11, q1);
}

__global__ __attribute__((amdgpu_flat_work_group_size(256, 256),
                          amdgpu_waves_per_eu(1, 2)))
void fuse2_kernel(const float* __restrict__ pos,
    const float* __restrict__ c1, const float* __restrict__ w11, const float* __restrict__ b11,
    float* __restrict__ c2, int* __restrict__ nbr1, int* __restrict__ cnt1,
    float* __restrict__ t1buf, float rr1) {
  int bid = blockIdx.x;
  if (bid < 8)
    fps2_one(c1 + (size_t)bid * 2048 * 3, c2 + (size_t)bid * 512 * 3);
  else if (bid < 8 + 4096)
    ballquery_body<4096, 2048, 512, 4>(bid - 8, pos, c1, rr1, nbr1, cnt1);
  else
    t1_body(bid - (8 + 4096), c1, w11, b11, t1buf);
}

__global__ __launch_bounds__(256) void fuse3_kernel(const float* __restrict__ q1buf,
    const float* __restrict__ t1buf, const int* __restrict__ nbr1, const int* __restrict__ cnt1,
    const float* __restrict__ w12, const float* __restrict__ b12, float* __restrict__ x1,
    const float* __restrict__ c1, const float* __restrict__ c2, float rr2,
    int* __restrict__ nbr2, int* __restrict__ cnt2,
    const float* __restrict__ w21, const float* __restrict__ b21, float* __restrict__ t2buf,
    float* __restrict__ xin3) {
  int bid = blockIdx.x;
  if (bid < 4096)
    sa_pool_body<64, 128, 128, 4096, 2048>(bid, q1buf, t1buf, nbr1, cnt1, w12, b12, x1);
  else if (bid < 4096 + 1024)
    ballquery_body<2048, 512, 1024, 4>(bid - 4096, c1, c2, rr2, nbr2, cnt2);
  else if (bid < 4096 + 1024 + 1024)
    t2_body(bid - (4096 + 1024), c2, w21, b21, t2buf);
  else
    concat3_body(bid - (4096 + 1024 + 1024), c2, xin3);
}

// SA2 layer-1 q: q2[j] = [x1_j,p1_j] @ W1 (131->128)
__global__ __launch_bounds__(256) void q2_kernel(const float* __restrict__ x1,
    const float* __restrict__ p1, const float* __restrict__ w, float* __restrict__ q2) {
  int gw = (blockIdx.x << 2) + (threadIdx.x >> 6), lane = threadIdx.x & 63;
  const float* xr = x1 + (size_t)gw * 128; const float* pr = p1 + (size_t)gw * 3;
  float a0 = 0.f, a1 = 0.f;
#pragma unroll 8
  for (int m = 0; m < 128; m++) {
    float v = xr[m];
    a0 = fmaf(v, w[m * 128 + lane], a0);
    a1 = fmaf(v, w[m * 128 + 64 + lane], a1);
  }
#pragma unroll
  for (int m = 0; m < 3; m++) {
    float v = pr[m];
    a0 = fmaf(v, w[(128 + m) * 128 + lane], a0);
    a1 = fmaf(v, w[(128 + m) * 128 + 64 + lane], a1);
  }
  q2[(size_t)gw * 128 + lane] = a0;
  q2[(size_t)gw * 128 + 64 + lane] = a1;
}

__global__ __launch_bounds__(256) void sa_pool2_kernel(const float* __restrict__ q,
    const float* __restrict__ t, const int* __restrict__ nbr, const int* __restrict__ cnt,
    const float* __restrict__ w2, const float* __restrict__ b2, float* __restrict__ out) {
  sa_pool_body<128, 256, 272, 2048, 512>(blockIdx.x, q, t, nbr, cnt, w2, b2, out);
}

// ---------------------------------------------------------------------------
// Tiled fp32 GEMM, 64x64 block tile, 256 threads (4x4 per thread), K-step 16.
// ---------------------------------------------------------------------------
template<int K, int KP, int N, int AST, bool RELU>
__global__ __launch_bounds__(256) void gemm64(const float* __restrict__ A,
    const float* __restrict__ W, const float* __restrict__ bias, float* __restrict__ C) {
  constexpr int NT = N / 64;
  const int bid = blockIdx.x, tid = threadIdx.x;
  const int tm = bid / NT, tn = bid % NT;
  __shared__ __align__(16) float As[16][68];
  __shared__ __align__(16) float Ws[16][68];
  const int arow = tid >> 2, acol = (tid & 3) << 2;
  const int wrow = tid >> 4, wcol = (tid & 15) << 2;
  const int ty = tid >> 4, tx = tid & 15;
  const float* Ap = A + (size_t)(tm * 64 + arow) * AST + acol;
  const float* Wp = W + (size_t)tn * 64 + wcol;
  float acc[4][4] = {};
  for (int k0 = 0; k0 < KP; k0 += 16) {
    float4 av = *(const float4*)(Ap + k0);
    As[acol + 0][arow] = av.x; As[acol + 1][arow] = av.y;
    As[acol + 2][arow] = av.z; As[acol + 3][arow] = av.w;
    int krow = k0 + wrow;
    float4 wv = make_float4(0.f, 0.f, 0.f, 0.f);
    if (krow < K) wv = *(const float4*)(Wp + (size_t)krow * N);
    *(float4*)(&Ws[wrow][wcol]) = wv;
    __syncthreads();
#pragma unroll
    for (int kk = 0; kk < 16; kk++) {
      float4 a4 = *(const float4*)(&As[kk][ty << 2]);
      float4 b4 = *(const float4*)(&Ws[kk][tx << 2]);
      float aa[4] = {a4.x, a4.y, a4.z, a4.w};
      float bb[4] = {b4.x, b4.y, b4.z, b4.w};
#pragma unroll
      for (int mm = 0; mm < 4; mm++)
#pragma unroll
        for (int nn = 0; nn < 4; nn++) acc[mm][nn] = fmaf(aa[mm], bb[nn], acc[mm][nn]);
    }
    __syncthreads();
  }
  const int m0 = tm * 64 + (ty << 2), n0 = tn * 64 + (tx << 2);
#pragma unroll
  for (int mm = 0; mm < 4; mm++) {
    float4 o;
    o.x = acc[mm][0] + bias[n0 + 0];
    o.y = acc[mm][1] + bias[n0 + 1];
    o.z = acc[mm][2] + bias[n0 + 2];
    o.w = acc[mm][3] + bias[n0 + 3];
    if (RELU) { o.x = fmaxf(o.x, 0.f); o.y = fmaxf(o.y, 0.f);
                o.z = fmaxf(o.z, 0.f); o.w = fmaxf(o.w, 0.f); }
    *(float4*)(C + (size_t)(m0 + mm) * N + n0) = o;
  }
}

// global max over 512 points per batch: [8,512,1024] -> [8,1024]
__global__ void gmax_kernel(const float* __restrict__ h, float* __restrict__ g) {
  int n = blockIdx.x * 256 + threadIdx.x;          // 8192 outputs
  int b = n >> 10, col = n & 1023;
  const float* p = h + ((size_t)b * 512) * 1024 + col;
  float m = -__builtin_inff();
  for (int j = 0; j < 512; j++) m = fmaxf(m, p[(size_t)j * 1024]);
  g[n] = m;
}

// head MLP: 1024 ->512 relu ->256 relu ->40. One block per batch.
__global__ __launch_bounds__(256) void head_kernel(const float* __restrict__ g,
    const float* __restrict__ w1, const float* __restrict__ b1,
    const float* __restrict__ w2, const float* __restrict__ b2,
    const float* __restrict__ w3, const float* __restrict__ b3,
    float* __restrict__ out) {
  int b = blockIdx.x, t = threadIdx.x;
  __shared__ float s1[1024];
  __shared__ float s2[512];
  *(float4*)(s1 + t * 4) = *(const float4*)(g + (size_t)b * 1024 + t * 4);
  __syncthreads();
  {
    float a0 = b1[t], a1 = b1[t + 256];
    for (int i = 0; i < 1024; i++) {
      float v = s1[i];
      a0 = fmaf(v, w1[(size_t)i * 512 + t], a0);
      a1 = fmaf(v, w1[(size_t)i * 512 + t + 256], a1);
    }
    s2[t] = fmaxf(a0, 0.f); s2[t + 256] = fmaxf(a1, 0.f);
  }
  __syncthreads();
  {
    float a = b2[t];
    for (int i = 0; i < 512; i++) a = fmaf(s2[i], w2[(size_t)i * 256 + t], a);
    s1[t] = fmaxf(a, 0.f);
  }
  __syncthreads();
  if (t < 40) {
    float a = b3[t];
    for (int i = 0; i < 256; i++) a = fmaf(s1[i], w3[(size_t)i * 40 + t], a);
    out[(size_t)b * 40 + t] = a;
  }
}

// ===========================================================================
extern "C" void kernel_launch(void* const* d_in, const int* in_sizes, int n_in,
                              void* d_out, int out_size, void* d_ws, size_t ws_size,
                              hipStream_t stream) {
  const float* x   = (const float*)d_in[0];
  const float* pos = (const float*)d_in[1];
  const float* w11 = (const float*)d_in[2];  const float* b11 = (const float*)d_in[3];
  const float* w12 = (const float*)d_in[4];  const float* b12 = (const float*)d_in[5];
  const float* w21 = (const float*)d_in[6];  const float* b21 = (const float*)d_in[7];
  const float* w22 = (const float*)d_in[8];  const float* b22 = (const float*)d_in[9];
  const float* w31 = (const float*)d_in[10]; const float* b31 = (const float*)d_in[11];
  const float* w32 = (const float*)d_in[12]; const float* b32 = (const float*)d_in[13];
  const float* w33 = (const float*)d_in[14]; const float* b33 = (const float*)d_in[15];
  const float* hw1 = (const float*)d_in[16]; const float* hb1 = (const float*)d_in[17];
  const float* hw2 = (const float*)d_in[18]; const float* hb2 = (const float*)d_in[19];
  const float* hw3 = (const float*)d_in[20]; const float* hb3 = (const float*)d_in[21];
  float* out = (float*)d_out;

  // workspace layout (aliased by liveness); total ~41.7 MB
  char* wsb = (char*)d_ws;
  int*   cnt1 = (int*)(wsb + 81920);       // 64K
  int*   cnt2 = (int*)(wsb + 147456);      // 16K
  float* c1   = (float*)(wsb + 163840);    // 192K  (= p1)
  float* c2   = (float*)(wsb + 360448);    // 48K   (= p2)
  float* g    = (float*)(wsb + 409600);    // 32K
  char* big = wsb + 524288;
  int*   nbr1 = (int*)(big + 0);           // 4M   } dead after sa_pool1
  float* q1   = (float*)(big + 4194304);   // 8M   } -> h3c aliases (16M)
  float* t1   = (float*)(big + 12582912);  // 4M   }
  float* h3c  = (float*)(big + 0);
  float* x1   = (float*)(big + 16777216);  // 8M   } dead after q2/sa_pool2
  int*   nbr2 = (int*)(big + 25165824);    // 1M   } -> h3b aliases (8M)
  float* h3b  = (float*)(big + 16777216);
  float* q2   = (float*)(big + 26214400);  // 8M   -> h3a aliases (4M)
  float* h3a  = (float*)(big + 26214400);
  float* t2   = (float*)(big + 34603008);  // 2M
  float* xin3 = (float*)(big + 36700160);  // 4.45M  [8*512, 272]

  const float RR1 = (float)(0.2 * 0.2);    // match python-traced f32 constants
  const float RR2 = (float)(0.4 * 0.4);

  // ---- stage 1: fps1 (8 blocks, 1 batch each) || q1 ----
  fuse1_kernel<<<8 + 8192, 256, 0, stream>>>(pos, x, w11, c1, q1);
  // ---- stage 2: fps2 (8 blocks) || ballquery1 || t1 ----
  fuse2_kernel<<<8 + 4096 + 4096, 256, 0, stream>>>(pos, c1, w11, b11,
                                                    c2, nbr1, cnt1, t1, RR1);
  // ---- stage 3: sa_pool1 || ballquery2 || t2 || concat3 ----
  fuse3_kernel<<<4096 + 1024 + 1024 + 16, 256, 0, stream>>>(q1, t1, nbr1, cnt1,
      w12, b12, x1, c1, c2, RR2, nbr2, cnt2, w21, b21, t2, xin3);
  // ---- stage 4+: SA2 finish, global SA, head ----
  q2_kernel<<<4096, 256, 0, stream>>>(x1, c1, w21, q2);
  sa_pool2_kernel<<<1024, 256, 0, stream>>>(q2, t2, nbr2, cnt2, w22, b22, xin3);
  gemm64<259, 272, 256, 272, true ><<<256,  256, 0, stream>>>(xin3, w31, b31, h3a);
  gemm64<256, 256, 512, 256, true ><<<512,  256, 0, stream>>>(h3a,  w32, b32, h3b);
  gemm64<512, 512, 1024, 512, false><<<1024, 256, 0, stream>>>(h3b, w33, b33, h3c);
  gmax_kernel<<<32, 256, 0, stream>>>(h3c, g);
  head_kernel<<<NBATCH, 256, 0, stream>>>(g, hw1, hb1, hw2, hb2, hw3, hb3, out);

  (void)in_sizes; (void)n_in; (void)out_size; (void)ws_size;
}

// Round 12
// 3418.584 us; speedup vs baseline: 2.4969x; 1.0576x over previous
//
#include <hip/hip_runtime.h>

// ============================================================================
// PointNet++ (8 batches, N=4096) forward on MI355X — full pipeline, fp32.
// Round 12: round-11 stage split with the stage4 grid-size bug fixed
// (bq2/t2 need 1024 blocks each — 4096 centers at 4 waves/block; r11 gave
// them 256 -> poisoned nbr2 -> OOB read in sa_pool2 -> core dump).
//   fuse1  = fps1 || q1
//   stage2 = bq1 || t1
//   stage3 = fps2 || sa_pool1
//   stage4 = bq2 || t2 || q2 || concat3
//   stage5 = sa_pool2 ; then gemms/gmax/head.
// ============================================================================

constexpr int NBATCH = 8;

// ---- DPP wave64 reduction helpers -----------------------------------------
template<int CTRL>
__device__ __forceinline__ float dpp_max_step(float v) {
  int o = __builtin_amdgcn_update_dpp(__float_as_int(v), __float_as_int(v),
                                      CTRL, 0xf, 0xf, false);  // invalid -> old(=v)
  return fmaxf(v, __int_as_float(o));
}
__device__ __forceinline__ float wave_max_bcast(float v) {
  v = dpp_max_step<0x111>(v);  // row_shr:1
  v = dpp_max_step<0x112>(v);  // row_shr:2
  v = dpp_max_step<0x114>(v);  // row_shr:4
  v = dpp_max_step<0x118>(v);  // row_shr:8
  v = dpp_max_step<0x142>(v);  // row_bcast:15
  v = dpp_max_step<0x143>(v);  // row_bcast:31
  return __int_as_float(__builtin_amdgcn_readlane(__float_as_int(v), 63));
}
template<int CTRL>
__device__ __forceinline__ int dpp_add_step(int v) {
  int o = __builtin_amdgcn_update_dpp(0, v, CTRL, 0xf, 0xf, true);  // invalid -> 0
  return v + o;
}
__device__ __forceinline__ int wave_sum_bcast(int v) {
  v = dpp_add_step<0x111>(v);
  v = dpp_add_step<0x112>(v);
  v = dpp_add_step<0x114>(v);
  v = dpp_add_step<0x118>(v);
  v = dpp_add_step<0x142>(v);
  v = dpp_add_step<0x143>(v);
  return __builtin_amdgcn_readlane(v, 63);
}

// ---------------------------------------------------------------------------
// fps1: one batch, NPTS=4096, 256 thr (4 waves, 1/SIMD), PT=16 scalar arrays.
// ---------------------------------------------------------------------------
__device__ void fps1_one(const float* __restrict__ p, float* __restrict__ cb) {
#pragma clang fp contract(off)
  constexpr int NTH = 256, PT = 16, NW = 4, NSAMP = 2048;
  __shared__ unsigned long long skey[2][NW];
  __shared__ float sxyz[2][NW][3];
  __shared__ float scb[NSAMP * 3];
  const int t = threadIdx.x, lane = t & 63, w = t >> 6;
  const float INF = __builtin_inff();
  float px[PT], py[PT], pz[PT], md[PT];
#pragma unroll
  for (int i = 0; i < PT; i++) {
    int j = t * PT + i;
    px[i] = p[j * 3 + 0]; py[i] = p[j * 3 + 1]; pz[i] = p[j * 3 + 2];
    md[i] = INF;
  }
  float cx = p[0], cy = p[1], cz = p[2];
  if (t == 0) { scb[0] = cx; scb[1] = cy; scb[2] = cz; }
  for (int s = 0; s < NSAMP - 1; ++s) {
#pragma unroll
    for (int i = 0; i < PT; i++) {
      float dx = px[i] - cx, dy = py[i] - cy, dz = pz[i] - cz;
      float d = (dx * dx + dy * dy) + dz * dz;   // contract off: match XLA order
      md[i] = fminf(md[i], d);
    }
    float m8[8];
#pragma unroll
    for (int i = 0; i < 8; i++) m8[i] = fmaxf(md[i], md[i + 8]);
    float m4[4];
#pragma unroll
    for (int i = 0; i < 4; i++) m4[i] = fmaxf(m8[i], m8[i + 4]);
    float bv = fmaxf(fmaxf(m4[0], m4[1]), fmaxf(m4[2], m4[3]));
    int bi = 0;
#pragma unroll
    for (int i = PT - 1; i >= 1; --i) if (md[i] == bv) bi = i;
    float wmax = wave_max_bcast(bv);
    unsigned long long ball = __ballot(bv == wmax);
    int fl = __ffsll((long long)ball) - 1;       // lowest lane = lowest index
    int ib = __builtin_amdgcn_readlane(bi, fl);  // wave-uniform slot
    int gidx = ((w << 6) + fl) * PT + ib;
    float sx = px[0], sy = py[0], sz = pz[0];
#pragma unroll
    for (int k = 1; k < PT; k++)
      if (ib == k) { sx = px[k]; sy = py[k]; sz = pz[k]; }
    sx = __int_as_float(__builtin_amdgcn_readlane(__float_as_int(sx), fl));
    sy = __int_as_float(__builtin_amdgcn_readlane(__float_as_int(sy), fl));
    sz = __int_as_float(__builtin_amdgcn_readlane(__float_as_int(sz), fl));
    if (lane == 0) {
      skey[s & 1][w] = (((unsigned long long)(unsigned)__float_as_int(wmax)) << 32)
                       | (unsigned)(~gidx);
      sxyz[s & 1][w][0] = sx; sxyz[s & 1][w][1] = sy; sxyz[s & 1][w][2] = sz;
    }
    __syncthreads();
    unsigned long long best = skey[s & 1][0];
    float nx = sxyz[s & 1][0][0], ny = sxyz[s & 1][0][1], nz = sxyz[s & 1][0][2];
#pragma unroll
    for (int q = 1; q < NW; q++) {
      unsigned long long k2 = skey[s & 1][q];
      bool gt = k2 > best;                       // max d-bits, ties -> min gidx
      best = gt ? k2 : best;
      nx = gt ? sxyz[s & 1][q][0] : nx;
      ny = gt ? sxyz[s & 1][q][1] : ny;
      nz = gt ? sxyz[s & 1][q][2] : nz;
    }
    cx = nx; cy = ny; cz = nz;
    if (t == 0) { scb[(s + 1) * 3 + 0] = cx; scb[(s + 1) * 3 + 1] = cy;
                  scb[(s + 1) * 3 + 2] = cz; }
  }
  __syncthreads();
  for (int i = t; i < NSAMP * 3; i += NTH) cb[i] = scb[i];
}

// ---- fps2: one batch, NPTS=2048, 256 thr, PT=8 scalar arrays, NSAMP=512 ----
__device__ void fps2_one(const float* __restrict__ p, float* __restrict__ cb) {
#pragma clang fp contract(off)
  constexpr int NTH = 256, PT = 8, NW = 4, NSAMP = 512;
  __shared__ unsigned long long skey2[2][NW];
  __shared__ float sxyz2[2][NW][3];
  __shared__ float scb2[NSAMP * 3];
  const int t = threadIdx.x, lane = t & 63, w = t >> 6;
  const float INF = __builtin_inff();
  float px[PT], py[PT], pz[PT], md[PT];
#pragma unroll
  for (int i = 0; i < PT; i++) {
    int j = t * PT + i;
    px[i] = p[j * 3 + 0]; py[i] = p[j * 3 + 1]; pz[i] = p[j * 3 + 2];
    md[i] = INF;
  }
  float cx = p[0], cy = p[1], cz = p[2];
  if (t == 0) { scb2[0] = cx; scb2[1] = cy; scb2[2] = cz; }
  for (int s = 0; s < NSAMP - 1; ++s) {
#pragma unroll
    for (int i = 0; i < PT; i++) {
      float dx = px[i] - cx, dy = py[i] - cy, dz = pz[i] - cz;
      float d = (dx * dx + dy * dy) + dz * dz;
      md[i] = fminf(md[i], d);
    }
    float m4[4];
#pragma unroll
    for (int i = 0; i < 4; i++) m4[i] = fmaxf(md[i], md[i + 4]);
    float bv = fmaxf(fmaxf(m4[0], m4[1]), fmaxf(m4[2], m4[3]));
    int bi = 0;
#pragma unroll
    for (int i = PT - 1; i >= 1; --i) if (md[i] == bv) bi = i;
    float wmax = wave_max_bcast(bv);
    unsigned long long ball = __ballot(bv == wmax);
    int fl = __ffsll((long long)ball) - 1;
    int ib = __builtin_amdgcn_readlane(bi, fl);
    int gidx = ((w << 6) + fl) * PT + ib;
    float sx = px[0], sy = py[0], sz = pz[0];
#pragma unroll
    for (int k = 1; k < PT; k++)
      if (ib == k) { sx = px[k]; sy = py[k]; sz = pz[k]; }
    sx = __int_as_float(__builtin_amdgcn_readlane(__float_as_int(sx), fl));
    sy = __int_as_float(__builtin_amdgcn_readlane(__float_as_int(sy), fl));
    sz = __int_as_float(__builtin_amdgcn_readlane(__float_as_int(sz), fl));
    if (lane == 0) {
      skey2[s & 1][w] = (((unsigned long long)(unsigned)__float_as_int(wmax)) << 32)
                        | (unsigned)(~gidx);
      sxyz2[s & 1][w][0] = sx; sxyz2[s & 1][w][1] = sy; sxyz2[s & 1][w][2] = sz;
    }
    __syncthreads();
    unsigned long long best = skey2[s & 1][0];
    float nx = sxyz2[s & 1][0][0], ny = sxyz2[s & 1][0][1], nz = sxyz2[s & 1][0][2];
#pragma unroll
    for (int q = 1; q < NW; q++) {
      unsigned long long k2 = skey2[s & 1][q];
      bool gt = k2 > best;
      best = gt ? k2 : best;
      nx = gt ? sxyz2[s & 1][q][0] : nx;
      ny = gt ? sxyz2[s & 1][q][1] : ny;
      nz = gt ? sxyz2[s & 1][q][2] : nz;
    }
    cx = nx; cy = ny; cz = nz;
    if (t == 0) { scb2[(s + 1) * 3 + 0] = cx; scb2[(s + 1) * 3 + 1] = cy;
                  scb2[(s + 1) * 3 + 2] = cz; }
  }
  __syncthreads();
  for (int i = t; i < NSAMP * 3; i += NTH) cb[i] = scb2[i];
}

// ---------------------------------------------------------------------------
// Ball query + exact 64 nearest within radius (one wave per center).
// ---------------------------------------------------------------------------
template<int NPTS, int SPB, int LCAP, int WPB>
__device__ void ballquery_body(int bb, const float* __restrict__ pts,
    const float* __restrict__ ctr, float rr,
    int* __restrict__ nbr, int* __restrict__ cnt_out) {
#pragma clang fp contract(off)
  constexpr int KREG = LCAP / 64;
  const int gw = bb * WPB + (threadIdx.x >> 6);
  const int lane = threadIdx.x & 63;
  const int b = gw / SPB;
  __shared__ unsigned long long list_[WPB][LCAP];
  unsigned long long* list = list_[threadIdx.x >> 6];
  const float* p = pts + (size_t)b * NPTS * 3;
  const float* c = ctr + (size_t)gw * 3;
  const float cx = c[0], cy = c[1], cz = c[2];
  const unsigned long long lmask = (1ull << lane) - 1ull;
  int cnt = 0;
  for (int j0 = 0; j0 < NPTS; j0 += 64) {
    int j = j0 + lane;
    float dx = p[j * 3 + 0] - cx, dy = p[j * 3 + 1] - cy, dz = p[j * 3 + 2] - cz;
    float d = (dx * dx + dy * dy) + dz * dz;
    bool in = (d <= rr);
    unsigned long long bal = __ballot(in);
    int pos = cnt + __popcll(bal & lmask);
    if (in && pos < LCAP)
      list[pos] = (((unsigned long long)__float_as_uint(d)) << 32) | (unsigned)j;
    cnt += __popcll(bal);
  }
  if (cnt > LCAP) cnt = LCAP;
  __syncthreads();
  int* nbrp = nbr + (size_t)gw * 64;
  const int nr = (cnt + 63) >> 6;
  unsigned long long key[KREG];
#pragma unroll
  for (int r = 0; r < KREG; r++) {
    int slot = r * 64 + lane;
    key[r] = (r < nr && slot < cnt) ? list[slot] : ~0ull;
  }
  if (cnt <= 64) {
    nbrp[lane] = (lane < cnt) ? (int)(unsigned)key[0] : 0;
    if (lane == 0) cnt_out[gw] = cnt;
    return;
  }
  // radix select on d2 bits (d2 < 2.0 -> bits 31:30 are 0)
  unsigned pref = 0; int cbase = 0;
  for (int bit = 29; bit >= 0; --bit) {
    int cc = 0;
#pragma unroll
    for (int r = 0; r < KREG; r++) if (r < nr) {
      unsigned db = (unsigned)(key[r] >> 32);
      cc += ((db >> bit) == (pref >> bit)) ? 1 : 0;
    }
    cc = wave_sum_bcast(cc);
    if (cbase + cc < 64) { cbase += cc; pref |= (1u << bit); }
  }
  int base = 0;
#pragma unroll
  for (int r = 0; r < KREG; r++) if (r < nr) {
    unsigned db = (unsigned)(key[r] >> 32);
    bool sel = db < pref;
    unsigned long long m = __ballot(sel);
    if (sel) nbrp[base + __popcll(m & lmask)] = (int)(unsigned)key[r];
    base += __popcll(m);
  }
  int need = 64 - base;
  for (int t2 = 0; t2 < need; ++t2) {
    unsigned besti = 0xffffffffu;
#pragma unroll
    for (int r = 0; r < KREG; r++) if (r < nr) {
      if ((unsigned)(key[r] >> 32) == pref) {
        unsigned v = (unsigned)key[r];
        besti = v < besti ? v : besti;
      }
    }
#pragma unroll
    for (int off = 32; off; off >>= 1) {
      unsigned o = __shfl_xor(besti, off, 64);
      besti = o < besti ? o : besti;
    }
    unsigned long long wk = (((unsigned long long)pref) << 32) | besti;
#pragma unroll
    for (int r = 0; r < KREG; r++) if (r < nr && key[r] == wk) key[r] = ~0ull;
    if (lane == 0) nbrp[base + t2] = (int)besti;
  }
  if (lane == 0) cnt_out[gw] = 64;
}

// ---- SA layer-1 split bodies (256-thr blocks: 4 waves each) ----------------
__device__ void q1_body(int bb, const float* __restrict__ x,
    const float* __restrict__ pos, const float* __restrict__ w, float* __restrict__ q) {
  int gw = (bb << 2) + (threadIdx.x >> 6), lane = threadIdx.x & 63;
  const float* xr = x + (size_t)gw * 3; const float* pr = pos + (size_t)gw * 3;
  float a = 0.f;
#pragma unroll
  for (int m = 0; m < 3; m++) a = fmaf(xr[m], w[m * 64 + lane], a);
#pragma unroll
  for (int m = 0; m < 3; m++) a = fmaf(pr[m], w[(3 + m) * 64 + lane], a);
  q[(size_t)gw * 64 + lane] = a;
}

__device__ void t1_body(int bb, const float* __restrict__ c1,
    const float* __restrict__ w, const float* __restrict__ b1, float* __restrict__ t) {
  int gw = (bb << 2) + (threadIdx.x >> 6), lane = threadIdx.x & 63;
  const float* cr = c1 + (size_t)gw * 3;
  float a = b1[lane];
#pragma unroll
  for (int m = 0; m < 3; m++) a = fmaf(-cr[m], w[(3 + m) * 64 + lane], a);
  t[(size_t)gw * 64 + lane] = a;
}

__device__ void t2_body(int bb, const float* __restrict__ c2,
    const float* __restrict__ w, const float* __restrict__ b1, float* __restrict__ t) {
  int gw = (bb << 2) + (threadIdx.x >> 6), lane = threadIdx.x & 63;
  const float* cr = c2 + (size_t)gw * 3;
  float a0 = b1[lane], a1 = b1[64 + lane];
#pragma unroll
  for (int m = 0; m < 3; m++) {
    a0 = fmaf(-cr[m], w[(128 + m) * 128 + lane], a0);
    a1 = fmaf(-cr[m], w[(128 + m) * 128 + 64 + lane], a1);
  }
  t[(size_t)gw * 128 + lane] = a0;
  t[(size_t)gw * 128 + 64 + lane] = a1;
}

__device__ void q2_body(int bb, const float* __restrict__ x1,
    const float* __restrict__ p1, const float* __restrict__ w, float* __restrict__ q2) {
  int gw = (bb << 2) + (threadIdx.x >> 6), lane = threadIdx.x & 63;
  const float* xr = x1 + (size_t)gw * 128; const float* pr = p1 + (size_t)gw * 3;
  float a0 = 0.f, a1 = 0.f;
#pragma unroll 8
  for (int m = 0; m < 128; m++) {
    float v = xr[m];
    a0 = fmaf(v, w[m * 128 + lane], a0);
    a1 = fmaf(v, w[m * 128 + 64 + lane], a1);
  }
#pragma unroll
  for (int m = 0; m < 3; m++) {
    float v = pr[m];
    a0 = fmaf(v, w[(128 + m) * 128 + lane], a0);
    a1 = fmaf(v, w[(128 + m) * 128 + 64 + lane], a1);
  }
  q2[(size_t)gw * 128 + lane] = a0;
  q2[(size_t)gw * 128 + 64 + lane] = a1;
}

__device__ void concat3_body(int bb, const float* __restrict__ c2, float* __restrict__ xin3) {
  int row = bb * 256 + threadIdx.x;
  if (row < NBATCH * 512) {
    float* o = xin3 + (size_t)row * 272 + 256;
    const float* c = c2 + (size_t)row * 3;
    o[0] = c[0]; o[1] = c[1]; o[2] = c[2];
#pragma unroll
    for (int i = 3; i < 16; i++) o[i] = 0.f;
  }
}

// ---------------------------------------------------------------------------
// Per-center: h1[k] = relu(q[nbr_k] + t_s); h2 = h1 @ W2 + b2; out = max_k h2.
// ---------------------------------------------------------------------------
template<int CIN, int COUT, int OSTR, int NPB, int SPB>
__device__ void sa_pool_body(int bb, const float* __restrict__ q,
    const float* __restrict__ t, const int* __restrict__ nbr, const int* __restrict__ cnt,
    const float* __restrict__ w2, const float* __restrict__ b2, float* __restrict__ out) {
  int gw = (bb << 2) + (threadIdx.x >> 6), lane = threadIdx.x & 63;
  int b = gw / SPB;
  int nk = nbr[(size_t)gw * 64 + lane];
  int c = cnt[gw];
  const float* qr = q + ((size_t)b * NPB + nk) * CIN;
  const float* tr = t + (size_t)gw * CIN;
  float h[CIN];
#pragma unroll
  for (int i = 0; i < CIN; i += 4) {
    float4 v = *(const float4*)(qr + i);
    h[i]     = fmaxf(v.x + tr[i], 0.f);
    h[i + 1] = fmaxf(v.y + tr[i + 1], 0.f);
    h[i + 2] = fmaxf(v.z + tr[i + 2], 0.f);
    h[i + 3] = fmaxf(v.w + tr[i + 3], 0.f);
  }
  bool valid = lane < c;
  float* op = out + (size_t)gw * OSTR;
#pragma unroll 1
  for (int nc = 0; nc < COUT; nc += 16) {
    float acc[16];
#pragma unroll
    for (int u = 0; u < 16; u++) acc[u] = b2[nc + u];
#pragma unroll
    for (int i = 0; i < CIN; i++) {
      const float* wr = w2 + (size_t)i * COUT + nc;
#pragma unroll
      for (int u = 0; u < 16; u++) acc[u] = fmaf(h[i], wr[u], acc[u]);
    }
#pragma unroll
    for (int u = 0; u < 16; u++) {
      float v = valid ? acc[u] : -__builtin_inff();
#pragma unroll
      for (int off = 32; off; off >>= 1) v = fmaxf(v, __shfl_xor(v, off, 64));
      acc[u] = v;
    }
    if (lane == 0) {
#pragma unroll
      for (int u = 0; u < 16; u += 4)
        *(float4*)(op + nc + u) = make_float4(acc[u], acc[u + 1], acc[u + 2], acc[u + 3]);
    }
  }
}

// ---- fused stage kernels ---------------------------------------------------
__global__ __attribute__((amdgpu_flat_work_group_size(256, 256),
                          amdgpu_waves_per_eu(1, 2)))
void fuse1_kernel(const float* __restrict__ pos,
    const float* __restrict__ x, const float* __restrict__ w11,
    float* __restrict__ c1, float* __restrict__ q1) {
  int bid = blockIdx.x;
  if (bid < 8)
    fps1_one(pos + (size_t)bid * 4096 * 3, c1 + (size_t)bid * 2048 * 3);
  else
    q1_body(bid - 8, x, pos, w11, q1);
}

// stage2 = bq1 || t1   (bq1: 4096 blocks x 4 waves = 16384 centers;
//                       t1: 4096 blocks x 4 gw = 16384)
__global__ __launch_bounds__(256) void stage2_kernel(const float* __restrict__ pos,
    const float* __restrict__ c1, const float* __restrict__ w11, const float* __restrict__ b11,
    int* __restrict__ nbr1, int* __restrict__ cnt1, float* __restrict__ t1buf, float rr1) {
  int bid = blockIdx.x;
  if (bid < 4096)
    ballquery_body<4096, 2048, 512, 4>(bid, pos, c1, rr1, nbr1, cnt1);
  else
    t1_body(bid - 4096, c1, w11, b11, t1buf);
}

// stage3 = fps2 || sa_pool1  (sa_pool1: 4096 blocks x 4 waves = 16384 centers)
__global__ __launch_bounds__(256) void stage3_kernel(const float* __restrict__ c1,
    float* __restrict__ c2,
    const float* __restrict__ q1buf, const float* __restrict__ t1buf,
    const int* __restrict__ nbr1, const int* __restrict__ cnt1,
    const float* __restrict__ w12, const float* __restrict__ b12, float* __restrict__ x1) {
  int bid = blockIdx.x;
  if (bid < 8)
    fps2_one(c1 + (size_t)bid * 2048 * 3, c2 + (size_t)bid * 512 * 3);
  else
    sa_pool_body<64, 128, 128, 4096, 2048>(bid - 8, q1buf, t1buf, nbr1, cnt1, w12, b12, x1);
}

// stage4 = bq2(1024 blk) || t2(1024 blk) || q2(4096 blk) || concat3(16 blk)
__global__ __launch_bounds__(256) void stage4_kernel(const float* __restrict__ c1,
    const float* __restrict__ c2, float rr2,
    int* __restrict__ nbr2, int* __restrict__ cnt2,
    const float* __restrict__ w21, const float* __restrict__ b21, float* __restrict__ t2buf,
    const float* __restrict__ x1, float* __restrict__ q2buf, float* __restrict__ xin3) {
  int bid = blockIdx.x;
  if (bid < 1024)
    ballquery_body<2048, 512, 1024, 4>(bid, c1, c2, rr2, nbr2, cnt2);
  else if (bid < 1024 + 1024)
    t2_body(bid - 1024, c2, w21, b21, t2buf);
  else if (bid < 1024 + 1024 + 4096)
    q2_body(bid - 2048, x1, c1, w21, q2buf);
  else
    concat3_body(bid - (1024 + 1024 + 4096), c2, xin3);
}

__global__ __launch_bounds__(256) void sa_pool2_kernel(const float* __restrict__ q,
    const float* __restrict__ t, const int* __restrict__ nbr, const int* __restrict__ cnt,
    const float* __restrict__ w2, const float* __restrict__ b2, float* __restrict__ out) {
  sa_pool_body<128, 256, 272, 2048, 512>(blockIdx.x, q, t, nbr, cnt, w2, b2, out);
}

// ---------------------------------------------------------------------------
// Tiled fp32 GEMM, 64x64 block tile, 256 threads (4x4 per thread), K-step 16.
// ---------------------------------------------------------------------------
template<int K, int KP, int N, int AST, bool RELU>
__global__ __launch_bounds__(256) void gemm64(const float* __restrict__ A,
    const float* __restrict__ W, const float* __restrict__ bias, float* __restrict__ C) {
  constexpr int NT = N / 64;
  const int bid = blockIdx.x, tid = threadIdx.x;
  const int tm = bid / NT, tn = bid % NT;
  __shared__ __align__(16) float As[16][68];
  __shared__ __align__(16) float Ws[16][68];
  const int arow = tid >> 2, acol = (tid & 3) << 2;
  const int wrow = tid >> 4, wcol = (tid & 15) << 2;
  const int ty = tid >> 4, tx = tid & 15;
  const float* Ap = A + (size_t)(tm * 64 + arow) * AST + acol;
  const float* Wp = W + (size_t)tn * 64 + wcol;
  float acc[4][4] = {};
  for (int k0 = 0; k0 < KP; k0 += 16) {
    float4 av = *(const float4*)(Ap + k0);
    As[acol + 0][arow] = av.x; As[acol + 1][arow] = av.y;
    As[acol + 2][arow] = av.z; As[acol + 3][arow] = av.w;
    int krow = k0 + wrow;
    float4 wv = make_float4(0.f, 0.f, 0.f, 0.f);
    if (krow < K) wv = *(const float4*)(Wp + (size_t)krow * N);
    *(float4*)(&Ws[wrow][wcol]) = wv;
    __syncthreads();
#pragma unroll
    for (int kk = 0; kk < 16; kk++) {
      float4 a4 = *(const float4*)(&As[kk][ty << 2]);
      float4 b4 = *(const float4*)(&Ws[kk][tx << 2]);
      float aa[4] = {a4.x, a4.y, a4.z, a4.w};
      float bb[4] = {b4.x, b4.y, b4.z, b4.w};
#pragma unroll
      for (int mm = 0; mm < 4; mm++)
#pragma unroll
        for (int nn = 0; nn < 4; nn++) acc[mm][nn] = fmaf(aa[mm], bb[nn], acc[mm][nn]);
    }
    __syncthreads();
  }
  const int m0 = tm * 64 + (ty << 2), n0 = tn * 64 + (tx << 2);
#pragma unroll
  for (int mm = 0; mm < 4; mm++) {
    float4 o;
    o.x = acc[mm][0] + bias[n0 + 0];
    o.y = acc[mm][1] + bias[n0 + 1];
    o.z = acc[mm][2] + bias[n0 + 2];
    o.w = acc[mm][3] + bias[n0 + 3];
    if (RELU) { o.x = fmaxf(o.x, 0.f); o.y = fmaxf(o.y, 0.f);
                o.z = fmaxf(o.z, 0.f); o.w = fmaxf(o.w, 0.f); }
    *(float4*)(C + (size_t)(m0 + mm) * N + n0) = o;
  }
}

// global max over 512 points per batch: [8,512,1024] -> [8,1024]
__global__ void gmax_kernel(const float* __restrict__ h, float* __restrict__ g) {
  int n = blockIdx.x * 256 + threadIdx.x;          // 8192 outputs
  int b = n >> 10, col = n & 1023;
  const float* p = h + ((size_t)b * 512) * 1024 + col;
  float m = -__builtin_inff();
  for (int j = 0; j < 512; j++) m = fmaxf(m, p[(size_t)j * 1024]);
  g[n] = m;
}

// head MLP: 1024 ->512 relu ->256 relu ->40. One block per batch.
__global__ __launch_bounds__(256) void head_kernel(const float* __restrict__ g,
    const float* __restrict__ w1, const float* __restrict__ b1,
    const float* __restrict__ w2, const float* __restrict__ b2,
    const float* __restrict__ w3, const float* __restrict__ b3,
    float* __restrict__ out) {
  int b = blockIdx.x, t = threadIdx.x;
  __shared__ float s1[1024];
  __shared__ float s2[512];
  *(float4*)(s1 + t * 4) = *(const float4*)(g + (size_t)b * 1024 + t * 4);
  __syncthreads();
  {
    float a0 = b1[t], a1 = b1[t + 256];
    for (int i = 0; i < 1024; i++) {
      float v = s1[i];
      a0 = fmaf(v, w1[(size_t)i * 512 + t], a0);
      a1 = fmaf(v, w1[(size_t)i * 512 + t + 256], a1);
    }
    s2[t] = fmaxf(a0, 0.f); s2[t + 256] = fmaxf(a1, 0.f);
  }
  __syncthreads();
  {
    float a = b2[t];
    for (int i = 0; i < 512; i++) a = fmaf(s2[i], w2[(size_t)i * 256 + t], a);
    s1[t] = fmaxf(a, 0.f);
  }
  __syncthreads();
  if (t < 40) {
    float a = b3[t];
    for (int i = 0; i < 256; i++) a = fmaf(s1[i], w3[(size_t)i * 40 + t], a);
    out[(size_t)b * 40 + t] = a;
  }
}

// ===========================================================================
extern "C" void kernel_launch(void* const* d_in, const int* in_sizes, int n_in,
                              void* d_out, int out_size, void* d_ws, size_t ws_size,
                              hipStream_t stream) {
  const float* x   = (const float*)d_in[0];
  const float* pos = (const float*)d_in[1];
  const float* w11 = (const float*)d_in[2];  const float* b11 = (const float*)d_in[3];
  const float* w12 = (const float*)d_in[4];  const float* b12 = (const float*)d_in[5];
  const float* w21 = (const float*)d_in[6];  const float* b21 = (const float*)d_in[7];
  const float* w22 = (const float*)d_in[8];  const float* b22 = (const float*)d_in[9];
  const float* w31 = (const float*)d_in[10]; const float* b31 = (const float*)d_in[11];
  const float* w32 = (const float*)d_in[12]; const float* b32 = (const float*)d_in[13];
  const float* w33 = (const float*)d_in[14]; const float* b33 = (const float*)d_in[15];
  const float* hw1 = (const float*)d_in[16]; const float* hb1 = (const float*)d_in[17];
  const float* hw2 = (const float*)d_in[18]; const float* hb2 = (const float*)d_in[19];
  const float* hw3 = (const float*)d_in[20]; const float* hb3 = (const float*)d_in[21];
  float* out = (float*)d_out;

  // workspace layout (aliased by liveness); total ~41.7 MB
  char* wsb = (char*)d_ws;
  int*   cnt1 = (int*)(wsb + 81920);       // 64K
  int*   cnt2 = (int*)(wsb + 147456);      // 16K
  float* c1   = (float*)(wsb + 163840);    // 192K  (= p1)
  float* c2   = (float*)(wsb + 360448);    // 48K   (= p2)
  float* g    = (float*)(wsb + 409600);    // 32K
  char* big = wsb + 524288;
  int*   nbr1 = (int*)(big + 0);           // 4M   } dead after sa_pool1
  float* q1   = (float*)(big + 4194304);   // 8M   } -> h3c aliases (16M)
  float* t1   = (float*)(big + 12582912);  // 4M   }
  float* h3c  = (float*)(big + 0);
  float* x1   = (float*)(big + 16777216);  // 8M   } dead after q2/sa_pool2
  int*   nbr2 = (int*)(big + 25165824);    // 1M   } -> h3b aliases (8M)
  float* h3b  = (float*)(big + 16777216);
  float* q2   = (float*)(big + 26214400);  // 8M   -> h3a aliases (4M)
  float* h3a  = (float*)(big + 26214400);
  float* t2   = (float*)(big + 34603008);  // 2M
  float* xin3 = (float*)(big + 36700160);  // 4.45M  [8*512, 272]

  const float RR1 = (float)(0.2 * 0.2);    // match python-traced f32 constants
  const float RR2 = (float)(0.4 * 0.4);

  // ---- stage 1: fps1 || q1 ----
  fuse1_kernel<<<8 + 8192, 256, 0, stream>>>(pos, x, w11, c1, q1);
  // ---- stage 2: bq1 || t1 ----
  stage2_kernel<<<4096 + 4096, 256, 0, stream>>>(pos, c1, w11, b11,
                                                 nbr1, cnt1, t1, RR1);
  // ---- stage 3: fps2 || sa_pool1 ----
  stage3_kernel<<<8 + 4096, 256, 0, stream>>>(c1, c2, q1, t1, nbr1, cnt1,
                                              w12, b12, x1);
  // ---- stage 4: bq2 || t2 || q2 || concat3 ----
  stage4_kernel<<<1024 + 1024 + 4096 + 16, 256, 0, stream>>>(c1, c2, RR2,
      nbr2, cnt2, w21, b21, t2, x1, q2, xin3);
  // ---- stage 5+: sa_pool2, global SA, head ----
  sa_pool2_kernel<<<1024, 256, 0, stream>>>(q2, t2, nbr2, cnt2, w22, b22, xin3);
  gemm64<259, 272, 256, 272, true ><<<256,  256, 0, stream>>>(xin3, w31, b31, h3a);
  gemm64<256, 256, 512, 256, true ><<<512,  256, 0, stream>>>(h3a,  w32, b32, h3b);
  gemm64<512, 512, 1024, 512, false><<<1024, 256, 0, stream>>>(h3b, w33, b33, h3c);
  gmax_kernel<<<32, 256, 0, stream>>>(h3c, g);
  head_kernel<<<NBATCH, 256, 0, stream>>>(g, hw1, hb1, hw2, hb2, hw3, hb3, out);

  (void)in_sizes; (void)n_in; (void)out_size; (void)ws_size;
}